// Round 5
// baseline (1100.772 us; speedup 1.0000x reference)
//
#include <hip/hip_runtime.h>

#define N_NODES 50000
#define N_EDGES 600000
#define DIM     128
#define RR      4
#define LL      2
#define GG      512
#define CC      8

typedef short bf16x8 __attribute__((ext_vector_type(8)));
typedef float f32x4  __attribute__((ext_vector_type(4)));

// ---------- bf16 <-> f32 helpers ----------
__device__ __forceinline__ float bf16_to_f(unsigned short u) {
    return __uint_as_float(((unsigned int)u) << 16);
}
__device__ __forceinline__ unsigned short f_to_bf16(float f) {
    unsigned int u = __float_as_uint(f);
    u += 0x7FFFu + ((u >> 16) & 1u);   // RNE
    return (unsigned short)(u >> 16);
}
__device__ __forceinline__ float loadf(const void* p, long i, int isbf) {
    if (isbf) return bf16_to_f(((const unsigned short*)p)[i]);
    return ((const float*)p)[i];
}
__device__ __forceinline__ void storef(void* p, long i, float v, int isbf) {
    if (isbf) ((unsigned short*)p)[i] = f_to_bf16(v);
    else      ((float*)p)[i] = v;
}

// ---------- dtype detection ----------
__global__ void cg_detect(const unsigned int* __restrict__ xw, int* __restrict__ flag) {
    __shared__ int cnt;
    if (threadIdx.x == 0) cnt = 0;
    __syncthreads();
    unsigned int w = xw[threadIdx.x];
    unsigned int e = (w >> 7) & 0xFFu;
    atomicAdd(&cnt, (e >= 110u && e <= 133u) ? 1 : 0);
    __syncthreads();
    if (threadIdx.x == 0) *flag = (cnt >= 128) ? 1 : 0;
}

__global__ void cg_zero_i(int* __restrict__ p, int n) {
    int t = blockIdx.x * 256 + threadIdx.x;
    if (t < n) p[t] = 0;
}

// ---------- CSR by dst ----------
__global__ void cg_hist(const int* __restrict__ edge_index, int* __restrict__ deg) {
    int e = blockIdx.x * 256 + threadIdx.x;
    if (e >= N_EDGES) return;
    atomicAdd(&deg[edge_index[N_EDGES + e]], 1);
}

#define SCAN_T 1024
__global__ void cg_scan(const int* __restrict__ deg, int* __restrict__ rowptr,
                        int* __restrict__ cursor) {
    __shared__ int part[SCAN_T];
    int tid = threadIdx.x;
    const int chunk = (N_NODES + SCAN_T - 1) / SCAN_T;
    int lo = tid * chunk;
    int hi = lo + chunk; if (hi > N_NODES) hi = N_NODES;
    int s = 0;
    for (int i = lo; i < hi; i++) s += deg[i];
    part[tid] = s;
    __syncthreads();
    for (int off = 1; off < SCAN_T; off <<= 1) {
        int add = (tid >= off) ? part[tid - off] : 0;
        __syncthreads();
        part[tid] += add;
        __syncthreads();
    }
    int run = (tid > 0) ? part[tid - 1] : 0;
    for (int i = lo; i < hi; i++) {
        rowptr[i] = run; cursor[i] = run;
        run += deg[i];
    }
    if (tid == SCAN_T - 1) rowptr[N_NODES] = part[SCAN_T - 1];
}

__global__ void cg_fill(const int* __restrict__ edge_index, const int* __restrict__ edge_type,
                        int* __restrict__ cursor, int* __restrict__ eidx) {
    int e = blockIdx.x * 256 + threadIdx.x;
    if (e >= N_EDGES) return;
    int d = edge_index[N_EDGES + e];
    int pos = atomicAdd(&cursor[d], 1);
    eidx[pos] = (edge_index[e] << 2) | edge_type[e];
}

// ---------- node-type buckets: ints[0..3]=cnt, [4..7]=cursor, [8..12]=start ----------
__global__ void cg_thist(const int* __restrict__ node_type, int* __restrict__ tb) {
    int n = blockIdx.x * 256 + threadIdx.x;
    if (n >= N_NODES) return;
    atomicAdd(&tb[node_type[n]], 1);
}
__global__ void cg_tscan(int* __restrict__ tb) {
    int run = 0;
    for (int t = 0; t < 4; t++) {
        tb[8 + t] = run;
        tb[4 + t] = run;
        run += tb[t];
    }
    tb[12] = run;
}
__global__ void cg_tfill(const int* __restrict__ node_type, int* __restrict__ tb,
                         int* __restrict__ tlist) {
    int n = blockIdx.x * 256 + threadIdx.x;
    if (n >= N_NODES) return;
    int pos = atomicAdd(&tb[4 + node_type[n]], 1);
    tlist[pos] = n;
}

// ---------- canonicalize x -> packed bf16 ----------
__global__ void cg_canon_x(const void* __restrict__ x, const int* __restrict__ flagp,
                           unsigned short* __restrict__ xb) {
    long t = (long)blockIdx.x * 256 + threadIdx.x;
    if (t >= (long)N_NODES * DIM) return;
    int isbf = *flagp;
    if (isbf) xb[t] = ((const unsigned short*)x)[t];
    else      xb[t] = f_to_bf16(((const float*)x)[t]);
}

// ---------- Wt[t][o][d] = bf16(W_het[t][d][o]) ----------
__global__ void cg_canon_W(const void* __restrict__ W_het, const int* __restrict__ flagp,
                           unsigned short* __restrict__ Wt) {
    int b = blockIdx.x;          // t*128 + o
    int o = b & 127;
    int t = b >> 7;
    int d = threadIdx.x;
    int isbf = *flagp;
    float v = loadf(W_het, ((long)t * DIM + d) * DIM + o, isbf);
    Wt[((long)t * DIM + o) * DIM + d] = f_to_bf16(v);
}

// ---------- bhf[t][o] fp32 ----------
__global__ void cg_canon_bh(const void* __restrict__ b_het, const int* __restrict__ flagp,
                            float* __restrict__ bhf) {
    int t = blockIdx.x, o = threadIdx.x;
    bhf[t * DIM + o] = loadf(b_het, t * DIM + o, *flagp);
}

// ---------- M2t[lr][o][d] = bf16( sum_k conv_W[l,r,d,k] * fuse_W[r*128+k,o] ) ----------
__global__ void cg_make_M2t(const void* __restrict__ conv_W, const void* __restrict__ fuse_W,
                            const int* __restrict__ flagp, unsigned short* __restrict__ M2t) {
    int b  = blockIdx.x;            // lr*128 + d
    int d  = b & 127;
    int lr = b >> 7;
    int r  = lr & 3;
    int o  = threadIdx.x;
    int isbf = *flagp;
    float acc = 0.0f;
    for (int k = 0; k < DIM; k++) {
        acc += loadf(conv_W, (long)(lr * DIM + d) * DIM + k, isbf)
             * loadf(fuse_W, (long)(r * DIM + k) * DIM + o, isbf);
    }
    M2t[((long)lr * DIM + o) * DIM + d] = f_to_bf16(acc);
}

// ---------- cvec[l,o] ----------
__global__ void cg_make_c(const void* __restrict__ conv_b, const void* __restrict__ fuse_W,
                          const void* __restrict__ fuse_b, const int* __restrict__ flagp,
                          float* __restrict__ cvec) {
    int l = blockIdx.x;
    int o = threadIdx.x;
    int isbf = *flagp;
    float acc = loadf(fuse_b, o, isbf);
    for (int rk = 0; rk < RR * DIM; rk++) {
        acc += loadf(conv_b, (long)l * RR * DIM + rk, isbf)
             * loadf(fuse_W, (long)rk * DIM + o, isbf);
    }
    cvec[l * DIM + o] = acc;
}

// ================= MFMA GEMM kernels =================
// Tile: 64 rows x 128 cols, K=128. 4 waves, each wave 16 rows x 128 cols.
// LDS pad +8 shorts per row (272 B stride, 16B-aligned).
#define APAD 136

// hetero: h[n,:] = x[n,:] @ W_het[t]^T-staged + b_het[t]; rows from tlist per type
__global__ void cg_hetero_mfma(const unsigned short* __restrict__ xb,
                               const unsigned short* __restrict__ Wt,
                               const float* __restrict__ bhf,
                               const int* __restrict__ tlist, const int* __restrict__ tb,
                               unsigned short* __restrict__ h) {
    int t = blockIdx.y;
    int rows_base = tb[8 + t] + blockIdx.x * 64;
    int rend = tb[8 + t + 1];
    if (rows_base >= rend) return;
    __shared__ unsigned short a_lds[64][APAD];
    __shared__ unsigned short b_lds[DIM][APAD];
    int tx = threadIdx.x;
    // stage B = Wt[t] (128x128 bf16)
    const unsigned short* Wsrc = Wt + (long)t * DIM * DIM;
    for (int i = tx; i < 2048; i += 256) {
        uint4 w = *(const uint4*)(Wsrc + i * 8);
        int o = i >> 4, d = (i & 15) * 8;
        *(uint4*)&b_lds[o][d] = w;
    }
    // stage A rows via tlist
    for (int i = tx; i < 1024; i += 256) {
        int row = i >> 4, seg = (i & 15) * 8;
        int gr = rows_base + row;
        uint4 w = make_uint4(0u, 0u, 0u, 0u);
        if (gr < rend) {
            int n = tlist[gr];
            w = *(const uint4*)(xb + (long)n * DIM + seg);
        }
        *(uint4*)&a_lds[row][seg] = w;
    }
    __syncthreads();
    int wv = tx >> 6, lane = tx & 63;
    int m16 = lane & 15, quad = lane >> 4;
    f32x4 acc[8];
#pragma unroll
    for (int c = 0; c < 8; c++) acc[c] = (f32x4){0.f, 0.f, 0.f, 0.f};
    for (int ks = 0; ks < 4; ks++) {
        int koff = ks * 32 + quad * 8;
        bf16x8 af = *(const bf16x8*)(const void*)&a_lds[wv * 16 + m16][koff];
#pragma unroll
        for (int c = 0; c < 8; c++) {
            bf16x8 bfr = *(const bf16x8*)(const void*)&b_lds[c * 16 + m16][koff];
            acc[c] = __builtin_amdgcn_mfma_f32_16x16x32_bf16(af, bfr, acc[c], 0, 0, 0);
        }
    }
#pragma unroll
    for (int c = 0; c < 8; c++) {
#pragma unroll
        for (int i = 0; i < 4; i++) {
            int row = wv * 16 + quad * 4 + i;
            int col = c * 16 + m16;
            int gr = rows_base + row;
            if (gr < rend) {
                int n = tlist[gr];
                h[(long)n * DIM + col] = f_to_bf16(acc[c][i] + bhf[t * DIM + col]);
            }
        }
    }
}

// pgemm: P[n, r*128+o] = sum_d h[n,d] * M2t[lr][o][d]
__global__ void cg_pgemm_mfma(const unsigned short* __restrict__ h,
                              const unsigned short* __restrict__ M2t, int l,
                              unsigned short* __restrict__ P) {
    int r  = blockIdx.y;
    int n0 = blockIdx.x * 64;
    __shared__ unsigned short a_lds[64][APAD];
    __shared__ unsigned short b_lds[DIM][APAD];
    int tx = threadIdx.x;
    const unsigned short* Bsrc = M2t + (long)(l * RR + r) * DIM * DIM;
    for (int i = tx; i < 2048; i += 256) {
        uint4 w = *(const uint4*)(Bsrc + i * 8);
        int o = i >> 4, d = (i & 15) * 8;
        *(uint4*)&b_lds[o][d] = w;
    }
    for (int i = tx; i < 1024; i += 256) {
        int row = i >> 4, seg = (i & 15) * 8;
        int n = n0 + row;
        uint4 w = make_uint4(0u, 0u, 0u, 0u);
        if (n < N_NODES) w = *(const uint4*)(h + (long)n * DIM + seg);
        *(uint4*)&a_lds[row][seg] = w;
    }
    __syncthreads();
    int wv = tx >> 6, lane = tx & 63;
    int m16 = lane & 15, quad = lane >> 4;
    f32x4 acc[8];
#pragma unroll
    for (int c = 0; c < 8; c++) acc[c] = (f32x4){0.f, 0.f, 0.f, 0.f};
    for (int ks = 0; ks < 4; ks++) {
        int koff = ks * 32 + quad * 8;
        bf16x8 af = *(const bf16x8*)(const void*)&a_lds[wv * 16 + m16][koff];
#pragma unroll
        for (int c = 0; c < 8; c++) {
            bf16x8 bfr = *(const bf16x8*)(const void*)&b_lds[c * 16 + m16][koff];
            acc[c] = __builtin_amdgcn_mfma_f32_16x16x32_bf16(af, bfr, acc[c], 0, 0, 0);
        }
    }
#pragma unroll
    for (int c = 0; c < 8; c++) {
#pragma unroll
        for (int i = 0; i < 4; i++) {
            int row = wv * 16 + quad * 4 + i;
            int col = c * 16 + m16;
            int n = n0 + row;
            if (n < N_NODES)
                P[(long)n * (RR * DIM) + r * DIM + col] = f_to_bf16(acc[c][i]);
        }
    }
}

// ---------- gather: 4 edges in flight per wave; h[n,:]=relu(sum P[src,r,:] + cv) ----------
__global__ void cg_gather4(const unsigned short* __restrict__ P, const int* __restrict__ rowptr,
                           const int* __restrict__ eidx, const float* __restrict__ cv,
                           unsigned short* __restrict__ hout) {
    int wid  = (blockIdx.x * 256 + threadIdx.x) >> 6;
    int lane = threadIdx.x & 63;
    if (wid >= N_NODES) return;
    int eg = lane >> 4;       // edge group 0..3
    int ol = lane & 15;       // covers o = ol*8 .. ol*8+7
    int start = rowptr[wid];
    int end   = rowptr[wid + 1];
    float a[8] = {0.f, 0.f, 0.f, 0.f, 0.f, 0.f, 0.f, 0.f};
    for (int j = start + eg; j < end; j += 4) {
        int v = eidx[j];
        const uint4 w = *(const uint4*)(P + (long)(v >> 2) * (RR * DIM) + (v & 3) * DIM + ol * 8);
        a[0] += bf16_to_f((unsigned short)(w.x & 0xFFFFu));
        a[1] += bf16_to_f((unsigned short)(w.x >> 16));
        a[2] += bf16_to_f((unsigned short)(w.y & 0xFFFFu));
        a[3] += bf16_to_f((unsigned short)(w.y >> 16));
        a[4] += bf16_to_f((unsigned short)(w.z & 0xFFFFu));
        a[5] += bf16_to_f((unsigned short)(w.z >> 16));
        a[6] += bf16_to_f((unsigned short)(w.w & 0xFFFFu));
        a[7] += bf16_to_f((unsigned short)(w.w >> 16));
    }
#pragma unroll
    for (int i = 0; i < 8; i++) {
        a[i] += __shfl_xor(a[i], 16);
        a[i] += __shfl_xor(a[i], 32);
    }
    if (eg == 0) {
        int o0 = ol * 8;
        float v[8];
#pragma unroll
        for (int i = 0; i < 8; i++) {
            float s = a[i] + cv[o0 + i];
            v[i] = s > 0.0f ? s : 0.0f;
        }
        uint4 o4;
        o4.x = (unsigned int)f_to_bf16(v[0]) | ((unsigned int)f_to_bf16(v[1]) << 16);
        o4.y = (unsigned int)f_to_bf16(v[2]) | ((unsigned int)f_to_bf16(v[3]) << 16);
        o4.z = (unsigned int)f_to_bf16(v[4]) | ((unsigned int)f_to_bf16(v[5]) << 16);
        o4.w = (unsigned int)f_to_bf16(v[6]) | ((unsigned int)f_to_bf16(v[7]) << 16);
        *(uint4*)(hout + (long)wid * DIM + o0) = o4;
    }
}

// ---------- pooling via sorted-batch binary search ----------
__global__ void cg_pool2(const unsigned short* __restrict__ h, const int* __restrict__ batch,
                         float* __restrict__ embacc, const int* __restrict__ flagp,
                         void* __restrict__ out) {
    int g = blockIdx.x;
    int o = threadIdx.x;
    int lo = 0, hi = N_NODES;
    while (lo < hi) { int mid = (lo + hi) >> 1; if (batch[mid] < g) lo = mid + 1; else hi = mid; }
    int start = lo;
    hi = N_NODES;
    while (lo < hi) { int mid = (lo + hi) >> 1; if (batch[mid] < g + 1) lo = mid + 1; else hi = mid; }
    int end = lo;
    float acc = 0.0f;
    for (int n = start; n < end; n++) acc += bf16_to_f(h[(long)n * DIM + o]);
    int cnt = end - start;
    float e = acc / (float)(cnt > 1 ? cnt : 1);
    embacc[(long)g * DIM + o] = e;
    storef(out, (long)g * DIM + o, e, *flagp);
}

// ---------- logits ----------
__global__ void cg_logits(const float* __restrict__ emb, const void* __restrict__ cls_W,
                          const void* __restrict__ cls_b, const int* __restrict__ flagp,
                          void* __restrict__ out) {
    int t = blockIdx.x * 256 + threadIdx.x;
    if (t >= GG * CC) return;
    int g  = t >> 3;
    int cc = t & 7;
    int isbf = *flagp;
    float acc = loadf(cls_b, cc, isbf);
    for (int k = 0; k < DIM; k++) {
        acc += emb[(long)g * DIM + k] * loadf(cls_W, (long)k * CC + cc, isbf);
    }
    storef(out, (long)GG * DIM + t, acc, isbf);
}

extern "C" void kernel_launch(void* const* d_in, const int* in_sizes, int n_in,
                              void* d_out, int out_size, void* d_ws, size_t ws_size,
                              hipStream_t stream) {
    const void* x      = d_in[0];
    const void* W_het  = d_in[1];
    const void* b_het  = d_in[2];
    const void* conv_W = d_in[3];
    const void* conv_b = d_in[4];
    const void* fuse_W = d_in[5];
    const void* fuse_b = d_in[6];
    const void* cls_W  = d_in[7];
    const void* cls_b  = d_in[8];
    const int* node_type  = (const int*)d_in[9];
    const int* edge_index = (const int*)d_in[10];
    const int* edge_type  = (const int*)d_in[11];
    const int* batch      = (const int*)d_in[12];

    // workspace layout (bytes, 16B aligned)
    char* base = (char*)d_ws;
    unsigned short* hbf    = (unsigned short*)(base + 0);          // 12,800,000
    unsigned short* P      = (unsigned short*)(base + 12800000);   // 51,200,000
    unsigned short* xb     = (unsigned short*)(base + 64000000);   // 12,800,000
    unsigned short* Wt     = (unsigned short*)(base + 76800000);   //    131,072
    float*          bhf    = (float*)(base + 76931072);            //      2,048
    unsigned short* M2t    = (unsigned short*)(base + 76933120);   //    262,144
    float*          cvec   = (float*)(base + 77195264);            //      1,024
    float*          embacc = (float*)(base + 77196288);            //    262,144
    int*            rowptr = (int*)(base + 77458432);              //    200,032
    int*            cursor = (int*)(base + 77658464);              //    200,032
    int*            deg    = (int*)(base + 77858496);              //    200,032
    int*            eidx   = (int*)(base + 78058528);              //  2,400,000
    int*            tlist  = (int*)(base + 80458528);              //    200,000
    int*            tb     = (int*)(base + 80658528);              //         64 (cnt4|cur4|start5)
    int*            flag   = (int*)(base + 80658592);              //          4

    cg_detect<<<1, 256, 0, stream>>>((const unsigned int*)x, flag);

    // graph structure
    cg_zero_i<<<(N_NODES + 255) / 256, 256, 0, stream>>>(deg, N_NODES);
    cg_zero_i<<<1, 32, 0, stream>>>(tb, 16);
    cg_hist<<<(N_EDGES + 255) / 256, 256, 0, stream>>>(edge_index, deg);
    cg_scan<<<1, SCAN_T, 0, stream>>>(deg, rowptr, cursor);
    cg_fill<<<(N_EDGES + 255) / 256, 256, 0, stream>>>(edge_index, edge_type, cursor, eidx);
    cg_thist<<<(N_NODES + 255) / 256, 256, 0, stream>>>(node_type, tb);
    cg_tscan<<<1, 1, 0, stream>>>(tb);
    cg_tfill<<<(N_NODES + 255) / 256, 256, 0, stream>>>(node_type, tb, tlist);

    // canonicalization
    cg_canon_x<<<(int)(((long)N_NODES * DIM + 255) / 256), 256, 0, stream>>>(x, flag, xb);
    cg_canon_W<<<4 * DIM, DIM, 0, stream>>>(W_het, flag, Wt);
    cg_canon_bh<<<4, DIM, 0, stream>>>(b_het, flag, bhf);
    cg_make_M2t<<<LL * RR * DIM, DIM, 0, stream>>>(conv_W, fuse_W, flag, M2t);
    cg_make_c<<<LL, DIM, 0, stream>>>(conv_b, fuse_W, fuse_b, flag, cvec);

    // pipeline
    cg_hetero_mfma<<<dim3((N_NODES + 63) / 64, 4), 256, 0, stream>>>(
        xb, Wt, bhf, tlist, tb, hbf);
    for (int l = 0; l < LL; l++) {
        cg_pgemm_mfma<<<dim3((N_NODES + 63) / 64, RR), 256, 0, stream>>>(hbf, M2t, l, P);
        cg_gather4<<<(N_NODES * 64 + 255) / 256, 256, 0, stream>>>(
            P, rowptr, eidx, cvec + l * DIM, hbf);
    }

    cg_pool2<<<GG, DIM, 0, stream>>>(hbf, batch, embacc, flag, d_out);
    cg_logits<<<(GG * CC + 255) / 256, 256, 0, stream>>>(embacc, cls_W, cls_b, flag, d_out);
}

// Round 6
// 567.624 us; speedup vs baseline: 1.9393x; 1.9393x over previous
//
#include <hip/hip_runtime.h>

#define N_NODES 50000
#define N_EDGES 600000
#define DIM     128
#define RR      4
#define LL      2
#define GG      512
#define CC      8

typedef short bf16x8 __attribute__((ext_vector_type(8)));
typedef float f32x4  __attribute__((ext_vector_type(4)));

// ---------- bf16 <-> f32 helpers ----------
__device__ __forceinline__ float bf16_to_f(unsigned short u) {
    return __uint_as_float(((unsigned int)u) << 16);
}
__device__ __forceinline__ unsigned short f_to_bf16(float f) {
    unsigned int u = __float_as_uint(f);
    u += 0x7FFFu + ((u >> 16) & 1u);   // RNE
    return (unsigned short)(u >> 16);
}
__device__ __forceinline__ float loadf(const void* p, long i, int isbf) {
    if (isbf) return bf16_to_f(((const unsigned short*)p)[i]);
    return ((const float*)p)[i];
}
__device__ __forceinline__ void storef(void* p, long i, float v, int isbf) {
    if (isbf) ((unsigned short*)p)[i] = f_to_bf16(v);
    else      ((float*)p)[i] = v;
}

// ---------- dtype detection ----------
__global__ void cg_detect(const unsigned int* __restrict__ xw, int* __restrict__ flag) {
    __shared__ int cnt;
    if (threadIdx.x == 0) cnt = 0;
    __syncthreads();
    unsigned int w = xw[threadIdx.x];
    unsigned int e = (w >> 7) & 0xFFu;
    atomicAdd(&cnt, (e >= 110u && e <= 133u) ? 1 : 0);
    __syncthreads();
    if (threadIdx.x == 0) *flag = (cnt >= 128) ? 1 : 0;
}

__global__ void cg_zero_i(int* __restrict__ p, int n) {
    int t = blockIdx.x * 256 + threadIdx.x;
    if (t < n) p[t] = 0;
}

// ---------- CSR by dst ----------
__global__ void cg_hist(const int* __restrict__ edge_index, int* __restrict__ deg) {
    int e = blockIdx.x * 256 + threadIdx.x;
    if (e >= N_EDGES) return;
    atomicAdd(&deg[edge_index[N_EDGES + e]], 1);
}

#define SCAN_T 1024
__global__ void cg_scan(const int* __restrict__ deg, int* __restrict__ rowptr,
                        int* __restrict__ cursor) {
    __shared__ int part[SCAN_T];
    int tid = threadIdx.x;
    const int chunk = (N_NODES + SCAN_T - 1) / SCAN_T;
    int lo = tid * chunk;
    int hi = lo + chunk; if (hi > N_NODES) hi = N_NODES;
    int s = 0;
    for (int i = lo; i < hi; i++) s += deg[i];
    part[tid] = s;
    __syncthreads();
    for (int off = 1; off < SCAN_T; off <<= 1) {
        int add = (tid >= off) ? part[tid - off] : 0;
        __syncthreads();
        part[tid] += add;
        __syncthreads();
    }
    int run = (tid > 0) ? part[tid - 1] : 0;
    for (int i = lo; i < hi; i++) {
        rowptr[i] = run; cursor[i] = run;
        run += deg[i];
    }
    if (tid == SCAN_T - 1) rowptr[N_NODES] = part[SCAN_T - 1];
}

__global__ void cg_fill(const int* __restrict__ edge_index, const int* __restrict__ edge_type,
                        int* __restrict__ cursor, int* __restrict__ eidx) {
    int e = blockIdx.x * 256 + threadIdx.x;
    if (e >= N_EDGES) return;
    int d = edge_index[N_EDGES + e];
    int pos = atomicAdd(&cursor[d], 1);
    eidx[pos] = (edge_index[e] << 2) | edge_type[e];
}

// ---------- node-type buckets (block-aggregated; tb: [0..3]=cnt,[4..7]=cursor,[8..12]=start) ----------
__global__ void cg_thist(const int* __restrict__ node_type, int* __restrict__ tb) {
    __shared__ int loc[4];
    int tid = threadIdx.x;
    if (tid < 4) loc[tid] = 0;
    __syncthreads();
    int n = blockIdx.x * 256 + tid;
    if (n < N_NODES) atomicAdd(&loc[node_type[n]], 1);
    __syncthreads();
    if (tid < 4) atomicAdd(&tb[tid], loc[tid]);
}
__global__ void cg_tscan(int* __restrict__ tb) {
    int run = 0;
    for (int t = 0; t < 4; t++) {
        tb[8 + t] = run;
        tb[4 + t] = run;
        run += tb[t];
    }
    tb[12] = run;
}
__global__ void cg_tfill(const int* __restrict__ node_type, int* __restrict__ tb,
                         int* __restrict__ tlist) {
    __shared__ int lcur[4];
    __shared__ int lbase[4];
    int tid = threadIdx.x;
    if (tid < 4) lcur[tid] = 0;
    __syncthreads();
    int n = blockIdx.x * 256 + tid;
    int slot = -1, t = 0;
    if (n < N_NODES) {
        t = node_type[n];
        slot = atomicAdd(&lcur[t], 1);       // LDS atomic: cheap
    }
    __syncthreads();
    if (tid < 4) lbase[tid] = atomicAdd(&tb[4 + tid], lcur[tid]);  // 4 global RMW / block
    __syncthreads();
    if (n < N_NODES) tlist[lbase[t] + slot] = n;
}

// ---------- canonicalize x -> packed bf16 ----------
__global__ void cg_canon_x(const void* __restrict__ x, const int* __restrict__ flagp,
                           unsigned short* __restrict__ xb) {
    long t = (long)blockIdx.x * 256 + threadIdx.x;
    if (t >= (long)N_NODES * DIM) return;
    int isbf = *flagp;
    if (isbf) xb[t] = ((const unsigned short*)x)[t];
    else      xb[t] = f_to_bf16(((const float*)x)[t]);
}

// ---------- Wt[t][o][d] = bf16(W_het[t][d][o]) ----------
__global__ void cg_canon_W(const void* __restrict__ W_het, const int* __restrict__ flagp,
                           unsigned short* __restrict__ Wt) {
    int b = blockIdx.x;          // t*128 + o
    int o = b & 127;
    int t = b >> 7;
    int d = threadIdx.x;
    int isbf = *flagp;
    float v = loadf(W_het, ((long)t * DIM + d) * DIM + o, isbf);
    Wt[((long)t * DIM + o) * DIM + d] = f_to_bf16(v);
}

// ---------- bhf[t][o] fp32 ----------
__global__ void cg_canon_bh(const void* __restrict__ b_het, const int* __restrict__ flagp,
                            float* __restrict__ bhf) {
    int t = blockIdx.x, o = threadIdx.x;
    bhf[t * DIM + o] = loadf(b_het, t * DIM + o, *flagp);
}

// ---------- M2t[lr][o][d] = bf16( sum_k conv_W[l,r,d,k] * fuse_W[r*128+k,o] ) ----------
__global__ void cg_make_M2t(const void* __restrict__ conv_W, const void* __restrict__ fuse_W,
                            const int* __restrict__ flagp, unsigned short* __restrict__ M2t) {
    int b  = blockIdx.x;            // lr*128 + d
    int d  = b & 127;
    int lr = b >> 7;
    int r  = lr & 3;
    int o  = threadIdx.x;
    int isbf = *flagp;
    float acc = 0.0f;
    for (int k = 0; k < DIM; k++) {
        acc += loadf(conv_W, (long)(lr * DIM + d) * DIM + k, isbf)
             * loadf(fuse_W, (long)(r * DIM + k) * DIM + o, isbf);
    }
    M2t[((long)lr * DIM + o) * DIM + d] = f_to_bf16(acc);
}

// ---------- cvec[l,o] ----------
__global__ void cg_make_c(const void* __restrict__ conv_b, const void* __restrict__ fuse_W,
                          const void* __restrict__ fuse_b, const int* __restrict__ flagp,
                          float* __restrict__ cvec) {
    int l = blockIdx.x;
    int o = threadIdx.x;
    int isbf = *flagp;
    float acc = loadf(fuse_b, o, isbf);
    for (int rk = 0; rk < RR * DIM; rk++) {
        acc += loadf(conv_b, (long)l * RR * DIM + rk, isbf)
             * loadf(fuse_W, (long)rk * DIM + o, isbf);
    }
    cvec[l * DIM + o] = acc;
}

// ================= MFMA GEMM kernels =================
#define APAD 136

// hetero: h[n,:] = x[n,:] @ W_het[t]^T-staged + b_het[t]; rows from tlist per type
__global__ void cg_hetero_mfma(const unsigned short* __restrict__ xb,
                               const unsigned short* __restrict__ Wt,
                               const float* __restrict__ bhf,
                               const int* __restrict__ tlist, const int* __restrict__ tb,
                               unsigned short* __restrict__ h) {
    int t = blockIdx.y;
    int rows_base = tb[8 + t] + blockIdx.x * 64;
    int rend = tb[8 + t + 1];
    if (rows_base >= rend) return;
    __shared__ unsigned short a_lds[64][APAD];
    __shared__ unsigned short b_lds[DIM][APAD];
    int tx = threadIdx.x;
    const unsigned short* Wsrc = Wt + (long)t * DIM * DIM;
    for (int i = tx; i < 2048; i += 256) {
        uint4 w = *(const uint4*)(Wsrc + i * 8);
        int o = i >> 4, d = (i & 15) * 8;
        *(uint4*)&b_lds[o][d] = w;
    }
    for (int i = tx; i < 1024; i += 256) {
        int row = i >> 4, seg = (i & 15) * 8;
        int gr = rows_base + row;
        uint4 w = make_uint4(0u, 0u, 0u, 0u);
        if (gr < rend) {
            int n = tlist[gr];
            w = *(const uint4*)(xb + (long)n * DIM + seg);
        }
        *(uint4*)&a_lds[row][seg] = w;
    }
    __syncthreads();
    int wv = tx >> 6, lane = tx & 63;
    int m16 = lane & 15, quad = lane >> 4;
    f32x4 acc[8];
#pragma unroll
    for (int c = 0; c < 8; c++) acc[c] = (f32x4){0.f, 0.f, 0.f, 0.f};
    for (int ks = 0; ks < 4; ks++) {
        int koff = ks * 32 + quad * 8;
        bf16x8 af = *(const bf16x8*)(const void*)&a_lds[wv * 16 + m16][koff];
#pragma unroll
        for (int c = 0; c < 8; c++) {
            bf16x8 bfr = *(const bf16x8*)(const void*)&b_lds[c * 16 + m16][koff];
            acc[c] = __builtin_amdgcn_mfma_f32_16x16x32_bf16(af, bfr, acc[c], 0, 0, 0);
        }
    }
#pragma unroll
    for (int c = 0; c < 8; c++) {
#pragma unroll
        for (int i = 0; i < 4; i++) {
            int row = wv * 16 + quad * 4 + i;
            int col = c * 16 + m16;
            int gr = rows_base + row;
            if (gr < rend) {
                int n = tlist[gr];
                h[(long)n * DIM + col] = f_to_bf16(acc[c][i] + bhf[t * DIM + col]);
            }
        }
    }
}

// pgemm: P[n, r*128+o] = sum_d h[n,d] * M2t[lr][o][d]
__global__ void cg_pgemm_mfma(const unsigned short* __restrict__ h,
                              const unsigned short* __restrict__ M2t, int l,
                              unsigned short* __restrict__ P) {
    int r  = blockIdx.y;
    int n0 = blockIdx.x * 64;
    __shared__ unsigned short a_lds[64][APAD];
    __shared__ unsigned short b_lds[DIM][APAD];
    int tx = threadIdx.x;
    const unsigned short* Bsrc = M2t + (long)(l * RR + r) * DIM * DIM;
    for (int i = tx; i < 2048; i += 256) {
        uint4 w = *(const uint4*)(Bsrc + i * 8);
        int o = i >> 4, d = (i & 15) * 8;
        *(uint4*)&b_lds[o][d] = w;
    }
    for (int i = tx; i < 1024; i += 256) {
        int row = i >> 4, seg = (i & 15) * 8;
        int n = n0 + row;
        uint4 w = make_uint4(0u, 0u, 0u, 0u);
        if (n < N_NODES) w = *(const uint4*)(h + (long)n * DIM + seg);
        *(uint4*)&a_lds[row][seg] = w;
    }
    __syncthreads();
    int wv = tx >> 6, lane = tx & 63;
    int m16 = lane & 15, quad = lane >> 4;
    f32x4 acc[8];
#pragma unroll
    for (int c = 0; c < 8; c++) acc[c] = (f32x4){0.f, 0.f, 0.f, 0.f};
    for (int ks = 0; ks < 4; ks++) {
        int koff = ks * 32 + quad * 8;
        bf16x8 af = *(const bf16x8*)(const void*)&a_lds[wv * 16 + m16][koff];
#pragma unroll
        for (int c = 0; c < 8; c++) {
            bf16x8 bfr = *(const bf16x8*)(const void*)&b_lds[c * 16 + m16][koff];
            acc[c] = __builtin_amdgcn_mfma_f32_16x16x32_bf16(af, bfr, acc[c], 0, 0, 0);
        }
    }
#pragma unroll
    for (int c = 0; c < 8; c++) {
#pragma unroll
        for (int i = 0; i < 4; i++) {
            int row = wv * 16 + quad * 4 + i;
            int col = c * 16 + m16;
            int n = n0 + row;
            if (n < N_NODES)
                P[(long)n * (RR * DIM) + r * DIM + col] = f_to_bf16(acc[c][i]);
        }
    }
}

// ---------- gather: 4 edges in flight per wave; h[n,:]=relu(sum P[src,r,:] + cv) ----------
__global__ void cg_gather4(const unsigned short* __restrict__ P, const int* __restrict__ rowptr,
                           const int* __restrict__ eidx, const float* __restrict__ cv,
                           unsigned short* __restrict__ hout) {
    int wid  = (blockIdx.x * 256 + threadIdx.x) >> 6;
    int lane = threadIdx.x & 63;
    if (wid >= N_NODES) return;
    int eg = lane >> 4;       // edge group 0..3
    int ol = lane & 15;       // covers o = ol*8 .. ol*8+7
    int start = rowptr[wid];
    int end   = rowptr[wid + 1];
    float a[8] = {0.f, 0.f, 0.f, 0.f, 0.f, 0.f, 0.f, 0.f};
    for (int j = start + eg; j < end; j += 4) {
        int v = eidx[j];
        const uint4 w = *(const uint4*)(P + (long)(v >> 2) * (RR * DIM) + (v & 3) * DIM + ol * 8);
        a[0] += bf16_to_f((unsigned short)(w.x & 0xFFFFu));
        a[1] += bf16_to_f((unsigned short)(w.x >> 16));
        a[2] += bf16_to_f((unsigned short)(w.y & 0xFFFFu));
        a[3] += bf16_to_f((unsigned short)(w.y >> 16));
        a[4] += bf16_to_f((unsigned short)(w.z & 0xFFFFu));
        a[5] += bf16_to_f((unsigned short)(w.z >> 16));
        a[6] += bf16_to_f((unsigned short)(w.w & 0xFFFFu));
        a[7] += bf16_to_f((unsigned short)(w.w >> 16));
    }
#pragma unroll
    for (int i = 0; i < 8; i++) {
        a[i] += __shfl_xor(a[i], 16);
        a[i] += __shfl_xor(a[i], 32);
    }
    if (eg == 0) {
        int o0 = ol * 8;
        float v[8];
#pragma unroll
        for (int i = 0; i < 8; i++) {
            float s = a[i] + cv[o0 + i];
            v[i] = s > 0.0f ? s : 0.0f;
        }
        uint4 o4;
        o4.x = (unsigned int)f_to_bf16(v[0]) | ((unsigned int)f_to_bf16(v[1]) << 16);
        o4.y = (unsigned int)f_to_bf16(v[2]) | ((unsigned int)f_to_bf16(v[3]) << 16);
        o4.z = (unsigned int)f_to_bf16(v[4]) | ((unsigned int)f_to_bf16(v[5]) << 16);
        o4.w = (unsigned int)f_to_bf16(v[6]) | ((unsigned int)f_to_bf16(v[7]) << 16);
        *(uint4*)(hout + (long)wid * DIM + o0) = o4;
    }
}

// ---------- pooling via sorted-batch binary search ----------
__global__ void cg_pool2(const unsigned short* __restrict__ h, const int* __restrict__ batch,
                         float* __restrict__ embacc, const int* __restrict__ flagp,
                         void* __restrict__ out) {
    int g = blockIdx.x;
    int o = threadIdx.x;
    int lo = 0, hi = N_NODES;
    while (lo < hi) { int mid = (lo + hi) >> 1; if (batch[mid] < g) lo = mid + 1; else hi = mid; }
    int start = lo;
    hi = N_NODES;
    while (lo < hi) { int mid = (lo + hi) >> 1; if (batch[mid] < g + 1) lo = mid + 1; else hi = mid; }
    int end = lo;
    float acc = 0.0f;
    for (int n = start; n < end; n++) acc += bf16_to_f(h[(long)n * DIM + o]);
    int cnt = end - start;
    float e = acc / (float)(cnt > 1 ? cnt : 1);
    embacc[(long)g * DIM + o] = e;
    storef(out, (long)g * DIM + o, e, *flagp);
}

// ---------- logits ----------
__global__ void cg_logits(const float* __restrict__ emb, const void* __restrict__ cls_W,
                          const void* __restrict__ cls_b, const int* __restrict__ flagp,
                          void* __restrict__ out) {
    int t = blockIdx.x * 256 + threadIdx.x;
    if (t >= GG * CC) return;
    int g  = t >> 3;
    int cc = t & 7;
    int isbf = *flagp;
    float acc = loadf(cls_b, cc, isbf);
    for (int k = 0; k < DIM; k++) {
        acc += emb[(long)g * DIM + k] * loadf(cls_W, (long)k * CC + cc, isbf);
    }
    storef(out, (long)GG * DIM + t, acc, isbf);
}

extern "C" void kernel_launch(void* const* d_in, const int* in_sizes, int n_in,
                              void* d_out, int out_size, void* d_ws, size_t ws_size,
                              hipStream_t stream) {
    const void* x      = d_in[0];
    const void* W_het  = d_in[1];
    const void* b_het  = d_in[2];
    const void* conv_W = d_in[3];
    const void* conv_b = d_in[4];
    const void* fuse_W = d_in[5];
    const void* fuse_b = d_in[6];
    const void* cls_W  = d_in[7];
    const void* cls_b  = d_in[8];
    const int* node_type  = (const int*)d_in[9];
    const int* edge_index = (const int*)d_in[10];
    const int* edge_type  = (const int*)d_in[11];
    const int* batch      = (const int*)d_in[12];

    // workspace layout (bytes, 16B aligned)
    char* base = (char*)d_ws;
    unsigned short* hbf    = (unsigned short*)(base + 0);          // 12,800,000
    unsigned short* P      = (unsigned short*)(base + 12800000);   // 51,200,000
    unsigned short* xb     = (unsigned short*)(base + 64000000);   // 12,800,000
    unsigned short* Wt     = (unsigned short*)(base + 76800000);   //    131,072
    float*          bhf    = (float*)(base + 76931072);            //      2,048
    unsigned short* M2t    = (unsigned short*)(base + 76933120);   //    262,144
    float*          cvec   = (float*)(base + 77195264);            //      1,024
    float*          embacc = (float*)(base + 77196288);            //    262,144
    int*            rowptr = (int*)(base + 77458432);              //    200,032
    int*            cursor = (int*)(base + 77658464);              //    200,032
    int*            deg    = (int*)(base + 77858496);              //    200,032
    int*            eidx   = (int*)(base + 78058528);              //  2,400,000
    int*            tlist  = (int*)(base + 80458528);              //    200,000
    int*            tb     = (int*)(base + 80658528);              //         64
    int*            flag   = (int*)(base + 80658592);              //          4

    cg_detect<<<1, 256, 0, stream>>>((const unsigned int*)x, flag);

    // graph structure
    cg_zero_i<<<(N_NODES + 255) / 256, 256, 0, stream>>>(deg, N_NODES);
    cg_zero_i<<<1, 32, 0, stream>>>(tb, 16);
    cg_hist<<<(N_EDGES + 255) / 256, 256, 0, stream>>>(edge_index, deg);
    cg_scan<<<1, SCAN_T, 0, stream>>>(deg, rowptr, cursor);
    cg_fill<<<(N_EDGES + 255) / 256, 256, 0, stream>>>(edge_index, edge_type, cursor, eidx);
    cg_thist<<<(N_NODES + 255) / 256, 256, 0, stream>>>(node_type, tb);
    cg_tscan<<<1, 1, 0, stream>>>(tb);
    cg_tfill<<<(N_NODES + 255) / 256, 256, 0, stream>>>(node_type, tb, tlist);

    // canonicalization
    cg_canon_x<<<(int)(((long)N_NODES * DIM + 255) / 256), 256, 0, stream>>>(x, flag, xb);
    cg_canon_W<<<4 * DIM, DIM, 0, stream>>>(W_het, flag, Wt);
    cg_canon_bh<<<4, DIM, 0, stream>>>(b_het, flag, bhf);
    cg_make_M2t<<<LL * RR * DIM, DIM, 0, stream>>>(conv_W, fuse_W, flag, M2t);
    cg_make_c<<<LL, DIM, 0, stream>>>(conv_b, fuse_W, fuse_b, flag, cvec);

    // pipeline
    cg_hetero_mfma<<<dim3((N_NODES + 63) / 64, 4), 256, 0, stream>>>(
        xb, Wt, bhf, tlist, tb, hbf);
    for (int l = 0; l < LL; l++) {
        cg_pgemm_mfma<<<dim3((N_NODES + 63) / 64, RR), 256, 0, stream>>>(hbf, M2t, l, P);
        cg_gather4<<<(N_NODES * 64 + 255) / 256, 256, 0, stream>>>(
            P, rowptr, eidx, cvec + l * DIM, hbf);
    }

    cg_pool2<<<GG, DIM, 0, stream>>>(hbf, batch, embacc, flag, d_out);
    cg_logits<<<(GG * CC + 255) / 256, 256, 0, stream>>>(embacc, cls_W, cls_b, flag, d_out);
}

// Round 8
// 455.980 us; speedup vs baseline: 2.4141x; 1.2448x over previous
//
#include <hip/hip_runtime.h>

#define N_NODES 50000
#define N_EDGES 600000
#define DIM     128
#define RR      4
#define LL      2
#define GG      512
#define CC      8
#define NB_SCAN ((N_NODES + 255) / 256)   // 196

typedef short bf16x8 __attribute__((ext_vector_type(8)));
typedef float f32x4  __attribute__((ext_vector_type(4)));

// ---------- bf16 <-> f32 helpers ----------
__device__ __forceinline__ float bf16_to_f(unsigned short u) {
    return __uint_as_float(((unsigned int)u) << 16);
}
__device__ __forceinline__ unsigned short f_to_bf16(float f) {
    unsigned int u = __float_as_uint(f);
    u += 0x7FFFu + ((u >> 16) & 1u);   // RNE
    return (unsigned short)(u >> 16);
}
__device__ __forceinline__ float loadf(const void* p, long i, int isbf) {
    if (isbf) return bf16_to_f(((const unsigned short*)p)[i]);
    return ((const float*)p)[i];
}
__device__ __forceinline__ void storef(void* p, long i, float v, int isbf) {
    if (isbf) ((unsigned short*)p)[i] = f_to_bf16(v);
    else      ((float*)p)[i] = v;
}

// ---------- dtype detection ----------
__global__ void cg_detect(const unsigned int* __restrict__ xw, int* __restrict__ flag) {
    __shared__ int cnt;
    if (threadIdx.x == 0) cnt = 0;
    __syncthreads();
    unsigned int w = xw[threadIdx.x];
    unsigned int e = (w >> 7) & 0xFFu;
    atomicAdd(&cnt, (e >= 110u && e <= 133u) ? 1 : 0);
    __syncthreads();
    if (threadIdx.x == 0) *flag = (cnt >= 128) ? 1 : 0;
}

__global__ void cg_zero_i(int* __restrict__ p, int n) {
    int t = blockIdx.x * 256 + threadIdx.x;
    if (t < n) p[t] = 0;
}

// ---------- histograms: edge-dst degree + node-type (block-aggregated) ----------
__global__ void cg_hist2(const int* __restrict__ edge_index, const int* __restrict__ node_type,
                         int* __restrict__ deg, int* __restrict__ tb) {
    __shared__ int loc[4];
    int tid = threadIdx.x;
    if (tid < 4) loc[tid] = 0;
    __syncthreads();
    int e = blockIdx.x * 256 + tid;
    if (e < N_EDGES) atomicAdd(&deg[edge_index[N_EDGES + e]], 1);
    if (e < N_NODES) atomicAdd(&loc[node_type[e]], 1);
    __syncthreads();
    if (tid < 4 && loc[tid]) atomicAdd(&tb[tid], loc[tid]);
}

// ---------- device-wide exclusive scan, 3 phases ----------
__global__ void cg_scan_a(const int* __restrict__ deg, int* __restrict__ blocksum) {
    __shared__ int s[256];
    int tid = threadIdx.x;
    int i = blockIdx.x * 256 + tid;
    s[tid] = (i < N_NODES) ? deg[i] : 0;
    __syncthreads();
    for (int off = 128; off > 0; off >>= 1) {
        if (tid < off) s[tid] += s[tid + off];
        __syncthreads();
    }
    if (tid == 0) blocksum[blockIdx.x] = s[0];
}

__global__ void cg_scan_b(const int* __restrict__ blocksum, int* __restrict__ blockoff,
                          int* __restrict__ rowptr, int* __restrict__ tb) {
    __shared__ int s[256];
    int tid = threadIdx.x;
    int v = (tid < NB_SCAN) ? blocksum[tid] : 0;
    s[tid] = v;
    __syncthreads();
    for (int off = 1; off < 256; off <<= 1) {
        int a = (tid >= off) ? s[tid - off] : 0;
        __syncthreads();
        s[tid] += a;
        __syncthreads();
    }
    if (tid < NB_SCAN) blockoff[tid] = s[tid] - v;   // exclusive
    if (tid == 255) rowptr[N_NODES] = s[255];        // total = E
    if (tid == 0) {                                   // fold the tiny type-bucket scan
        int run = 0;
        for (int t = 0; t < 4; t++) {
            tb[8 + t] = run;
            tb[4 + t] = run;
            run += tb[t];
        }
        tb[12] = run;
    }
}

__global__ void cg_scan_c(const int* __restrict__ deg, const int* __restrict__ blockoff,
                          int* __restrict__ rowptr, int* __restrict__ cursor) {
    __shared__ int s[256];
    int tid = threadIdx.x;
    int i = blockIdx.x * 256 + tid;
    int v = (i < N_NODES) ? deg[i] : 0;
    s[tid] = v;
    __syncthreads();
    for (int off = 1; off < 256; off <<= 1) {
        int a = (tid >= off) ? s[tid - off] : 0;
        __syncthreads();
        s[tid] += a;
        __syncthreads();
    }
    if (i < N_NODES) {
        int val = blockoff[blockIdx.x] + s[tid] - v;  // exclusive
        rowptr[i] = val;
        cursor[i] = val;
    }
}

__global__ void cg_fill(const int* __restrict__ edge_index, const int* __restrict__ edge_type,
                        int* __restrict__ cursor, int* __restrict__ eidx) {
    int e = blockIdx.x * 256 + threadIdx.x;
    if (e >= N_EDGES) return;
    int d = edge_index[N_EDGES + e];
    int pos = atomicAdd(&cursor[d], 1);
    eidx[pos] = (edge_index[e] << 2) | edge_type[e];
}

// ---------- node-type list fill (block-aggregated) ----------
__global__ void cg_tfill(const int* __restrict__ node_type, int* __restrict__ tb,
                         int* __restrict__ tlist) {
    __shared__ int lcur[4];
    __shared__ int lbase[4];
    int tid = threadIdx.x;
    if (tid < 4) lcur[tid] = 0;
    __syncthreads();
    int n = blockIdx.x * 256 + tid;
    int slot = -1, t = 0;
    if (n < N_NODES) {
        t = node_type[n];
        slot = atomicAdd(&lcur[t], 1);
    }
    __syncthreads();
    if (tid < 4) lbase[tid] = atomicAdd(&tb[4 + tid], lcur[tid]);
    __syncthreads();
    if (n < N_NODES) tlist[lbase[t] + slot] = n;
}

// ---------- canonicalize x -> packed bf16 ----------
__global__ void cg_canon_x(const void* __restrict__ x, const int* __restrict__ flagp,
                           unsigned short* __restrict__ xb) {
    long t = (long)blockIdx.x * 256 + threadIdx.x;
    if (t >= (long)N_NODES * DIM) return;
    int isbf = *flagp;
    if (isbf) xb[t] = ((const unsigned short*)x)[t];
    else      xb[t] = f_to_bf16(((const float*)x)[t]);
}

// ---------- Wt[t][o][d] = bf16(W_het[t][d][o]) ----------
__global__ void cg_canon_W(const void* __restrict__ W_het, const int* __restrict__ flagp,
                           unsigned short* __restrict__ Wt) {
    int b = blockIdx.x;          // t*128 + o
    int o = b & 127;
    int t = b >> 7;
    int d = threadIdx.x;
    int isbf = *flagp;
    float v = loadf(W_het, ((long)t * DIM + d) * DIM + o, isbf);
    Wt[((long)t * DIM + o) * DIM + d] = f_to_bf16(v);
}

// ---------- bhf[t][o] fp32 ----------
__global__ void cg_canon_bh(const void* __restrict__ b_het, const int* __restrict__ flagp,
                            float* __restrict__ bhf) {
    int t = blockIdx.x, o = threadIdx.x;
    bhf[t * DIM + o] = loadf(b_het, t * DIM + o, *flagp);
}

// ---------- M2t[lr][o][d] = bf16( sum_k conv_W[l,r,d,k] * fuse_W[r*128+k,o] ) ----------
__global__ void cg_make_M2t(const void* __restrict__ conv_W, const void* __restrict__ fuse_W,
                            const int* __restrict__ flagp, unsigned short* __restrict__ M2t) {
    int b  = blockIdx.x;            // lr*128 + d
    int d  = b & 127;
    int lr = b >> 7;
    int r  = lr & 3;
    int o  = threadIdx.x;
    int isbf = *flagp;
    float acc = 0.0f;
    for (int k = 0; k < DIM; k++) {
        acc += loadf(conv_W, (long)(lr * DIM + d) * DIM + k, isbf)
             * loadf(fuse_W, (long)(r * DIM + k) * DIM + o, isbf);
    }
    M2t[((long)lr * DIM + o) * DIM + d] = f_to_bf16(acc);
}

// ---------- cvec[l,o] ----------
__global__ void cg_make_c(const void* __restrict__ conv_b, const void* __restrict__ fuse_W,
                          const void* __restrict__ fuse_b, const int* __restrict__ flagp,
                          float* __restrict__ cvec) {
    int l = blockIdx.x;
    int o = threadIdx.x;
    int isbf = *flagp;
    float acc = loadf(fuse_b, o, isbf);
    for (int rk = 0; rk < RR * DIM; rk++) {
        acc += loadf(conv_b, (long)l * RR * DIM + rk, isbf)
             * loadf(fuse_W, (long)rk * DIM + o, isbf);
    }
    cvec[l * DIM + o] = acc;
}

// ================= MFMA GEMM kernels =================
#define APAD 136

__global__ void cg_hetero_mfma(const unsigned short* __restrict__ xb,
                               const unsigned short* __restrict__ Wt,
                               const float* __restrict__ bhf,
                               const int* __restrict__ tlist, const int* __restrict__ tb,
                               unsigned short* __restrict__ h) {
    int t = blockIdx.y;
    int rows_base = tb[8 + t] + blockIdx.x * 64;
    int rend = tb[8 + t + 1];
    if (rows_base >= rend) return;
    __shared__ unsigned short a_lds[64][APAD];
    __shared__ unsigned short b_lds[DIM][APAD];
    int tx = threadIdx.x;
    const unsigned short* Wsrc = Wt + (long)t * DIM * DIM;
    for (int i = tx; i < 2048; i += 256) {
        uint4 w = *(const uint4*)(Wsrc + i * 8);
        int o = i >> 4, d = (i & 15) * 8;
        *(uint4*)&b_lds[o][d] = w;
    }
    for (int i = tx; i < 1024; i += 256) {
        int row = i >> 4, seg = (i & 15) * 8;
        int gr = rows_base + row;
        uint4 w = make_uint4(0u, 0u, 0u, 0u);
        if (gr < rend) {
            int n = tlist[gr];
            w = *(const uint4*)(xb + (long)n * DIM + seg);
        }
        *(uint4*)&a_lds[row][seg] = w;
    }
    __syncthreads();
    int wv = tx >> 6, lane = tx & 63;
    int m16 = lane & 15, quad = lane >> 4;
    f32x4 acc[8];
#pragma unroll
    for (int c = 0; c < 8; c++) acc[c] = (f32x4){0.f, 0.f, 0.f, 0.f};
    for (int ks = 0; ks < 4; ks++) {
        int koff = ks * 32 + quad * 8;
        bf16x8 af = *(const bf16x8*)(const void*)&a_lds[wv * 16 + m16][koff];
#pragma unroll
        for (int c = 0; c < 8; c++) {
            bf16x8 bfr = *(const bf16x8*)(const void*)&b_lds[c * 16 + m16][koff];
            acc[c] = __builtin_amdgcn_mfma_f32_16x16x32_bf16(af, bfr, acc[c], 0, 0, 0);
        }
    }
#pragma unroll
    for (int c = 0; c < 8; c++) {
#pragma unroll
        for (int i = 0; i < 4; i++) {
            int row = wv * 16 + quad * 4 + i;
            int col = c * 16 + m16;
            int gr = rows_base + row;
            if (gr < rend) {
                int n = tlist[gr];
                h[(long)n * DIM + col] = f_to_bf16(acc[c][i] + bhf[t * DIM + col]);
            }
        }
    }
}

__global__ void cg_pgemm_mfma(const unsigned short* __restrict__ h,
                              const unsigned short* __restrict__ M2t, int l,
                              unsigned short* __restrict__ P) {
    int r  = blockIdx.y;
    int n0 = blockIdx.x * 64;
    __shared__ unsigned short a_lds[64][APAD];
    __shared__ unsigned short b_lds[DIM][APAD];
    int tx = threadIdx.x;
    const unsigned short* Bsrc = M2t + (long)(l * RR + r) * DIM * DIM;
    for (int i = tx; i < 2048; i += 256) {
        uint4 w = *(const uint4*)(Bsrc + i * 8);
        int o = i >> 4, d = (i & 15) * 8;
        *(uint4*)&b_lds[o][d] = w;
    }
    for (int i = tx; i < 1024; i += 256) {
        int row = i >> 4, seg = (i & 15) * 8;
        int n = n0 + row;
        uint4 w = make_uint4(0u, 0u, 0u, 0u);
        if (n < N_NODES) w = *(const uint4*)(h + (long)n * DIM + seg);
        *(uint4*)&a_lds[row][seg] = w;
    }
    __syncthreads();
    int wv = tx >> 6, lane = tx & 63;
    int m16 = lane & 15, quad = lane >> 4;
    f32x4 acc[8];
#pragma unroll
    for (int c = 0; c < 8; c++) acc[c] = (f32x4){0.f, 0.f, 0.f, 0.f};
    for (int ks = 0; ks < 4; ks++) {
        int koff = ks * 32 + quad * 8;
        bf16x8 af = *(const bf16x8*)(const void*)&a_lds[wv * 16 + m16][koff];
#pragma unroll
        for (int c = 0; c < 8; c++) {
            bf16x8 bfr = *(const bf16x8*)(const void*)&b_lds[c * 16 + m16][koff];
            acc[c] = __builtin_amdgcn_mfma_f32_16x16x32_bf16(af, bfr, acc[c], 0, 0, 0);
        }
    }
#pragma unroll
    for (int c = 0; c < 8; c++) {
#pragma unroll
        for (int i = 0; i < 4; i++) {
            int row = wv * 16 + quad * 4 + i;
            int col = c * 16 + m16;
            int n = n0 + row;
            if (n < N_NODES)
                P[(long)n * (RR * DIM) + r * DIM + col] = f_to_bf16(acc[c][i]);
        }
    }
}

// ---------- gather: 4 edges in flight per wave ----------
__global__ void cg_gather4(const unsigned short* __restrict__ P, const int* __restrict__ rowptr,
                           const int* __restrict__ eidx, const float* __restrict__ cv,
                           unsigned short* __restrict__ hout) {
    int wid  = (blockIdx.x * 256 + threadIdx.x) >> 6;
    int lane = threadIdx.x & 63;
    if (wid >= N_NODES) return;
    int eg = lane >> 4;
    int ol = lane & 15;
    int start = rowptr[wid];
    int end   = rowptr[wid + 1];
    float a[8] = {0.f, 0.f, 0.f, 0.f, 0.f, 0.f, 0.f, 0.f};
    for (int j = start + eg; j < end; j += 4) {
        int v = eidx[j];
        const uint4 w = *(const uint4*)(P + (long)(v >> 2) * (RR * DIM) + (v & 3) * DIM + ol * 8);
        a[0] += bf16_to_f((unsigned short)(w.x & 0xFFFFu));
        a[1] += bf16_to_f((unsigned short)(w.x >> 16));
        a[2] += bf16_to_f((unsigned short)(w.y & 0xFFFFu));
        a[3] += bf16_to_f((unsigned short)(w.y >> 16));
        a[4] += bf16_to_f((unsigned short)(w.z & 0xFFFFu));
        a[5] += bf16_to_f((unsigned short)(w.z >> 16));
        a[6] += bf16_to_f((unsigned short)(w.w & 0xFFFFu));
        a[7] += bf16_to_f((unsigned short)(w.w >> 16));
    }
#pragma unroll
    for (int i = 0; i < 8; i++) {
        a[i] += __shfl_xor(a[i], 16);
        a[i] += __shfl_xor(a[i], 32);
    }
    if (eg == 0) {
        int o0 = ol * 8;
        float v[8];
#pragma unroll
        for (int i = 0; i < 8; i++) {
            float s = a[i] + cv[o0 + i];
            v[i] = s > 0.0f ? s : 0.0f;
        }
        uint4 o4;
        o4.x = (unsigned int)f_to_bf16(v[0]) | ((unsigned int)f_to_bf16(v[1]) << 16);
        o4.y = (unsigned int)f_to_bf16(v[2]) | ((unsigned int)f_to_bf16(v[3]) << 16);
        o4.z = (unsigned int)f_to_bf16(v[4]) | ((unsigned int)f_to_bf16(v[5]) << 16);
        o4.w = (unsigned int)f_to_bf16(v[6]) | ((unsigned int)f_to_bf16(v[7]) << 16);
        *(uint4*)(hout + (long)wid * DIM + o0) = o4;
    }
}

// ---------- pooling via sorted-batch binary search ----------
__global__ void cg_pool2(const unsigned short* __restrict__ h, const int* __restrict__ batch,
                         float* __restrict__ embacc, const int* __restrict__ flagp,
                         void* __restrict__ out) {
    int g = blockIdx.x;
    int o = threadIdx.x;
    int lo = 0, hi = N_NODES;
    while (lo < hi) { int mid = (lo + hi) >> 1; if (batch[mid] < g) lo = mid + 1; else hi = mid; }
    int start = lo;
    hi = N_NODES;
    while (lo < hi) { int mid = (lo + hi) >> 1; if (batch[mid] < g + 1) lo = mid + 1; else hi = mid; }
    int end = lo;
    float acc = 0.0f;
    for (int n = start; n < end; n++) acc += bf16_to_f(h[(long)n * DIM + o]);
    int cnt = end - start;
    float e = acc / (float)(cnt > 1 ? cnt : 1);
    embacc[(long)g * DIM + o] = e;
    storef(out, (long)g * DIM + o, e, *flagp);
}

// ---------- logits ----------
__global__ void cg_logits(const float* __restrict__ emb, const void* __restrict__ cls_W,
                          const void* __restrict__ cls_b, const int* __restrict__ flagp,
                          void* __restrict__ out) {
    int t = blockIdx.x * 256 + threadIdx.x;
    if (t >= GG * CC) return;
    int g  = t >> 3;
    int cc = t & 7;
    int isbf = *flagp;
    float acc = loadf(cls_b, cc, isbf);
    for (int k = 0; k < DIM; k++) {
        acc += emb[(long)g * DIM + k] * loadf(cls_W, (long)k * CC + cc, isbf);
    }
    storef(out, (long)GG * DIM + t, acc, isbf);
}

extern "C" void kernel_launch(void* const* d_in, const int* in_sizes, int n_in,
                              void* d_out, int out_size, void* d_ws, size_t ws_size,
                              hipStream_t stream) {
    const void* x      = d_in[0];
    const void* W_het  = d_in[1];
    const void* b_het  = d_in[2];
    const void* conv_W = d_in[3];
    const void* conv_b = d_in[4];
    const void* fuse_W = d_in[5];
    const void* fuse_b = d_in[6];
    const void* cls_W  = d_in[7];
    const void* cls_b  = d_in[8];
    const int* node_type  = (const int*)d_in[9];
    const int* edge_index = (const int*)d_in[10];
    const int* edge_type  = (const int*)d_in[11];
    const int* batch      = (const int*)d_in[12];

    // workspace layout (bytes, 16B aligned); deg and tb adjacent for one zero pass
    char* base = (char*)d_ws;
    unsigned short* hbf      = (unsigned short*)(base + 0);          // 12,800,000
    unsigned short* P        = (unsigned short*)(base + 12800000);   // 51,200,000
    unsigned short* xb       = (unsigned short*)(base + 64000000);   // 12,800,000
    unsigned short* Wt       = (unsigned short*)(base + 76800000);   //    131,072
    float*          bhf      = (float*)(base + 76931072);            //      2,048
    unsigned short* M2t      = (unsigned short*)(base + 76933120);   //    262,144
    float*          cvec     = (float*)(base + 77195264);            //      1,024
    float*          embacc   = (float*)(base + 77196288);            //    262,144
    int*            rowptr   = (int*)(base + 77458432);              //    200,032
    int*            cursor   = (int*)(base + 77658464);              //    200,032
    int*            deg      = (int*)(base + 77858496);              //    200,000
    int*            tb       = (int*)(base + 78058496);              //         64
    int*            blocksum = (int*)(base + 78058560);              //      1,024
    int*            blockoff = (int*)(base + 78059584);              //      1,024
    int*            eidx     = (int*)(base + 78060608);              //  2,400,000
    int*            tlist    = (int*)(base + 80460608);              //    200,000
    int*            flag     = (int*)(base + 80660608);              //          4

    cg_detect<<<1, 256, 0, stream>>>((const unsigned int*)x, flag);

    // graph structure
    cg_zero_i<<<(N_NODES + 16 + 255) / 256, 256, 0, stream>>>(deg, N_NODES + 16);
    cg_hist2<<<(N_EDGES + 255) / 256, 256, 0, stream>>>(edge_index, node_type, deg, tb);
    cg_scan_a<<<NB_SCAN, 256, 0, stream>>>(deg, blocksum);
    cg_scan_b<<<1, 256, 0, stream>>>(blocksum, blockoff, rowptr, tb);
    cg_scan_c<<<NB_SCAN, 256, 0, stream>>>(deg, blockoff, rowptr, cursor);
    cg_fill<<<(N_EDGES + 255) / 256, 256, 0, stream>>>(edge_index, edge_type, cursor, eidx);
    cg_tfill<<<(N_NODES + 255) / 256, 256, 0, stream>>>(node_type, tb, tlist);

    // canonicalization
    cg_canon_x<<<(int)(((long)N_NODES * DIM + 255) / 256), 256, 0, stream>>>(x, flag, xb);
    cg_canon_W<<<4 * DIM, DIM, 0, stream>>>(W_het, flag, Wt);
    cg_canon_bh<<<4, DIM, 0, stream>>>(b_het, flag, bhf);
    cg_make_M2t<<<LL * RR * DIM, DIM, 0, stream>>>(conv_W, fuse_W, flag, M2t);
    cg_make_c<<<LL, DIM, 0, stream>>>(conv_b, fuse_W, fuse_b, flag, cvec);

    // pipeline
    cg_hetero_mfma<<<dim3((N_NODES + 63) / 64, 4), 256, 0, stream>>>(
        xb, Wt, bhf, tlist, tb, hbf);
    for (int l = 0; l < LL; l++) {
        cg_pgemm_mfma<<<dim3((N_NODES + 63) / 64, RR), 256, 0, stream>>>(hbf, M2t, l, P);
        cg_gather4<<<(N_NODES * 64 + 255) / 256, 256, 0, stream>>>(
            P, rowptr, eidx, cvec + l * DIM, hbf);
    }

    cg_pool2<<<GG, DIM, 0, stream>>>(hbf, batch, embacc, flag, d_out);
    cg_logits<<<(GG * CC + 255) / 256, 256, 0, stream>>>(embacc, cls_W, cls_b, flag, d_out);
}

// Round 9
// 407.762 us; speedup vs baseline: 2.6995x; 1.1183x over previous
//
#include <hip/hip_runtime.h>

#define N_NODES 50000
#define N_EDGES 600000
#define DIM     128
#define RR      4
#define LL      2
#define GG      512
#define CC      8
#define NB_SCAN ((N_NODES + 255) / 256)   // 196

typedef short bf16x8 __attribute__((ext_vector_type(8)));
typedef float f32x4  __attribute__((ext_vector_type(4)));

// ---------- bf16 <-> f32 helpers ----------
__device__ __forceinline__ float bf16_to_f(unsigned short u) {
    return __uint_as_float(((unsigned int)u) << 16);
}
__device__ __forceinline__ unsigned short f_to_bf16(float f) {
    unsigned int u = __float_as_uint(f);
    u += 0x7FFFu + ((u >> 16) & 1u);   // RNE
    return (unsigned short)(u >> 16);
}
__device__ __forceinline__ float loadf(const void* p, long i, int isbf) {
    if (isbf) return bf16_to_f(((const unsigned short*)p)[i]);
    return ((const float*)p)[i];
}
__device__ __forceinline__ void storef(void* p, long i, float v, int isbf) {
    if (isbf) ((unsigned short*)p)[i] = f_to_bf16(v);
    else      ((float*)p)[i] = v;
}

// ---------- dtype detection ----------
__global__ void cg_detect(const unsigned int* __restrict__ xw, int* __restrict__ flag) {
    __shared__ int cnt;
    if (threadIdx.x == 0) cnt = 0;
    __syncthreads();
    unsigned int w = xw[threadIdx.x];
    unsigned int e = (w >> 7) & 0xFFu;
    atomicAdd(&cnt, (e >= 110u && e <= 133u) ? 1 : 0);
    __syncthreads();
    if (threadIdx.x == 0) *flag = (cnt >= 128) ? 1 : 0;
}

__global__ void cg_zero_i(int* __restrict__ p, int n) {
    int t = blockIdx.x * 256 + threadIdx.x;
    if (t < n) p[t] = 0;
}

// ---------- histograms: edge-dst degree + node-type (block-aggregated) ----------
__global__ void cg_hist2(const int* __restrict__ edge_index, const int* __restrict__ node_type,
                         int* __restrict__ deg, int* __restrict__ tb) {
    __shared__ int loc[4];
    int tid = threadIdx.x;
    if (tid < 4) loc[tid] = 0;
    __syncthreads();
    int e = blockIdx.x * 256 + tid;
    if (e < N_EDGES) atomicAdd(&deg[edge_index[N_EDGES + e]], 1);
    if (e < N_NODES) atomicAdd(&loc[node_type[e]], 1);
    __syncthreads();
    if (tid < 4 && loc[tid]) atomicAdd(&tb[tid], loc[tid]);
}

// ---------- device-wide exclusive scan, 3 phases ----------
__global__ void cg_scan_a(const int* __restrict__ deg, int* __restrict__ blocksum) {
    __shared__ int s[256];
    int tid = threadIdx.x;
    int i = blockIdx.x * 256 + tid;
    s[tid] = (i < N_NODES) ? deg[i] : 0;
    __syncthreads();
    for (int off = 128; off > 0; off >>= 1) {
        if (tid < off) s[tid] += s[tid + off];
        __syncthreads();
    }
    if (tid == 0) blocksum[blockIdx.x] = s[0];
}

__global__ void cg_scan_b(const int* __restrict__ blocksum, int* __restrict__ blockoff,
                          int* __restrict__ rowptr, int* __restrict__ tb) {
    __shared__ int s[256];
    int tid = threadIdx.x;
    int v = (tid < NB_SCAN) ? blocksum[tid] : 0;
    s[tid] = v;
    __syncthreads();
    for (int off = 1; off < 256; off <<= 1) {
        int a = (tid >= off) ? s[tid - off] : 0;
        __syncthreads();
        s[tid] += a;
        __syncthreads();
    }
    if (tid < NB_SCAN) blockoff[tid] = s[tid] - v;   // exclusive
    if (tid == 255) rowptr[N_NODES] = s[255];        // total = E
    if (tid == 0) {                                   // fold the tiny type-bucket scan
        int run = 0;
        for (int t = 0; t < 4; t++) {
            tb[8 + t] = run;
            tb[4 + t] = run;
            run += tb[t];
        }
        tb[12] = run;
    }
}

__global__ void cg_scan_c(const int* __restrict__ deg, const int* __restrict__ blockoff,
                          int* __restrict__ rowptr, int* __restrict__ cursor) {
    __shared__ int s[256];
    int tid = threadIdx.x;
    int i = blockIdx.x * 256 + tid;
    int v = (i < N_NODES) ? deg[i] : 0;
    s[tid] = v;
    __syncthreads();
    for (int off = 1; off < 256; off <<= 1) {
        int a = (tid >= off) ? s[tid - off] : 0;
        __syncthreads();
        s[tid] += a;
        __syncthreads();
    }
    if (i < N_NODES) {
        int val = blockoff[blockIdx.x] + s[tid] - v;  // exclusive
        rowptr[i] = val;
        cursor[i] = val;
    }
}

__global__ void cg_fill(const int* __restrict__ edge_index, const int* __restrict__ edge_type,
                        int* __restrict__ cursor, int* __restrict__ eidx) {
    int e = blockIdx.x * 256 + threadIdx.x;
    if (e >= N_EDGES) return;
    int d = edge_index[N_EDGES + e];
    int pos = atomicAdd(&cursor[d], 1);
    eidx[pos] = (edge_index[e] << 2) | edge_type[e];
}

// ---------- node-type list fill (block-aggregated) ----------
__global__ void cg_tfill(const int* __restrict__ node_type, int* __restrict__ tb,
                         int* __restrict__ tlist) {
    __shared__ int lcur[4];
    __shared__ int lbase[4];
    int tid = threadIdx.x;
    if (tid < 4) lcur[tid] = 0;
    __syncthreads();
    int n = blockIdx.x * 256 + tid;
    int slot = -1, t = 0;
    if (n < N_NODES) {
        t = node_type[n];
        slot = atomicAdd(&lcur[t], 1);
    }
    __syncthreads();
    if (tid < 4) lbase[tid] = atomicAdd(&tb[4 + tid], lcur[tid]);
    __syncthreads();
    if (n < N_NODES) tlist[lbase[t] + slot] = n;
}

// ---------- canonicalize x -> packed bf16 ----------
__global__ void cg_canon_x(const void* __restrict__ x, const int* __restrict__ flagp,
                           unsigned short* __restrict__ xb) {
    long t = (long)blockIdx.x * 256 + threadIdx.x;
    if (t >= (long)N_NODES * DIM) return;
    int isbf = *flagp;
    if (isbf) xb[t] = ((const unsigned short*)x)[t];
    else      xb[t] = f_to_bf16(((const float*)x)[t]);
}

// ---------- Wt[t][o][d] = bf16(W_het[t][d][o]) ----------
__global__ void cg_canon_W(const void* __restrict__ W_het, const int* __restrict__ flagp,
                           unsigned short* __restrict__ Wt) {
    int b = blockIdx.x;          // t*128 + o
    int o = b & 127;
    int t = b >> 7;
    int d = threadIdx.x;
    int isbf = *flagp;
    float v = loadf(W_het, ((long)t * DIM + d) * DIM + o, isbf);
    Wt[((long)t * DIM + o) * DIM + d] = f_to_bf16(v);
}

// ---------- bhf[t][o] fp32 ----------
__global__ void cg_canon_bh(const void* __restrict__ b_het, const int* __restrict__ flagp,
                            float* __restrict__ bhf) {
    int t = blockIdx.x, o = threadIdx.x;
    bhf[t * DIM + o] = loadf(b_het, t * DIM + o, *flagp);
}

// ---------- M2t[lr][o][d] = bf16( sum_k conv_W[l,r,d,k] * fuse_W[r*128+k,o] ) ----------
__global__ void cg_make_M2t(const void* __restrict__ conv_W, const void* __restrict__ fuse_W,
                            const int* __restrict__ flagp, unsigned short* __restrict__ M2t) {
    int b  = blockIdx.x;            // lr*128 + d
    int d  = b & 127;
    int lr = b >> 7;
    int r  = lr & 3;
    int o  = threadIdx.x;
    int isbf = *flagp;
    float acc = 0.0f;
    for (int k = 0; k < DIM; k++) {
        acc += loadf(conv_W, (long)(lr * DIM + d) * DIM + k, isbf)
             * loadf(fuse_W, (long)(r * DIM + k) * DIM + o, isbf);
    }
    M2t[((long)lr * DIM + o) * DIM + d] = f_to_bf16(acc);
}

// ---------- cvec[l,o] = sum_rk conv_b[l,rk]*fuse_W[rk,o] + fuse_b[o] ----------
// one block per (l,o); 256 threads reduce the 512-term dot product
__global__ void cg_make_c(const void* __restrict__ conv_b, const void* __restrict__ fuse_W,
                          const void* __restrict__ fuse_b, const int* __restrict__ flagp,
                          float* __restrict__ cvec) {
    __shared__ float s[256];
    int b   = blockIdx.x;          // l*DIM + o
    int l   = b >> 7;
    int o   = b & 127;
    int tid = threadIdx.x;
    int isbf = *flagp;
    float part = 0.0f;
    for (int rk = tid; rk < RR * DIM; rk += 256) {   // 2 iterations
        part += loadf(conv_b, (long)l * RR * DIM + rk, isbf)
              * loadf(fuse_W, (long)rk * DIM + o, isbf);
    }
    s[tid] = part;
    __syncthreads();
    for (int off = 128; off > 0; off >>= 1) {
        if (tid < off) s[tid] += s[tid + off];
        __syncthreads();
    }
    if (tid == 0) cvec[b] = s[0] + loadf(fuse_b, o, isbf);
}

// ================= MFMA GEMM kernels =================
#define APAD 136

__global__ void cg_hetero_mfma(const unsigned short* __restrict__ xb,
                               const unsigned short* __restrict__ Wt,
                               const float* __restrict__ bhf,
                               const int* __restrict__ tlist, const int* __restrict__ tb,
                               unsigned short* __restrict__ h) {
    int t = blockIdx.y;
    int rows_base = tb[8 + t] + blockIdx.x * 64;
    int rend = tb[8 + t + 1];
    if (rows_base >= rend) return;
    __shared__ unsigned short a_lds[64][APAD];
    __shared__ unsigned short b_lds[DIM][APAD];
    int tx = threadIdx.x;
    const unsigned short* Wsrc = Wt + (long)t * DIM * DIM;
    for (int i = tx; i < 2048; i += 256) {
        uint4 w = *(const uint4*)(Wsrc + i * 8);
        int o = i >> 4, d = (i & 15) * 8;
        *(uint4*)&b_lds[o][d] = w;
    }
    for (int i = tx; i < 1024; i += 256) {
        int row = i >> 4, seg = (i & 15) * 8;
        int gr = rows_base + row;
        uint4 w = make_uint4(0u, 0u, 0u, 0u);
        if (gr < rend) {
            int n = tlist[gr];
            w = *(const uint4*)(xb + (long)n * DIM + seg);
        }
        *(uint4*)&a_lds[row][seg] = w;
    }
    __syncthreads();
    int wv = tx >> 6, lane = tx & 63;
    int m16 = lane & 15, quad = lane >> 4;
    f32x4 acc[8];
#pragma unroll
    for (int c = 0; c < 8; c++) acc[c] = (f32x4){0.f, 0.f, 0.f, 0.f};
    for (int ks = 0; ks < 4; ks++) {
        int koff = ks * 32 + quad * 8;
        bf16x8 af = *(const bf16x8*)(const void*)&a_lds[wv * 16 + m16][koff];
#pragma unroll
        for (int c = 0; c < 8; c++) {
            bf16x8 bfr = *(const bf16x8*)(const void*)&b_lds[c * 16 + m16][koff];
            acc[c] = __builtin_amdgcn_mfma_f32_16x16x32_bf16(af, bfr, acc[c], 0, 0, 0);
        }
    }
#pragma unroll
    for (int c = 0; c < 8; c++) {
#pragma unroll
        for (int i = 0; i < 4; i++) {
            int row = wv * 16 + quad * 4 + i;
            int col = c * 16 + m16;
            int gr = rows_base + row;
            if (gr < rend) {
                int n = tlist[gr];
                h[(long)n * DIM + col] = f_to_bf16(acc[c][i] + bhf[t * DIM + col]);
            }
        }
    }
}

__global__ void cg_pgemm_mfma(const unsigned short* __restrict__ h,
                              const unsigned short* __restrict__ M2t, int l,
                              unsigned short* __restrict__ P) {
    int r  = blockIdx.y;
    int n0 = blockIdx.x * 64;
    __shared__ unsigned short a_lds[64][APAD];
    __shared__ unsigned short b_lds[DIM][APAD];
    int tx = threadIdx.x;
    const unsigned short* Bsrc = M2t + (long)(l * RR + r) * DIM * DIM;
    for (int i = tx; i < 2048; i += 256) {
        uint4 w = *(const uint4*)(Bsrc + i * 8);
        int o = i >> 4, d = (i & 15) * 8;
        *(uint4*)&b_lds[o][d] = w;
    }
    for (int i = tx; i < 1024; i += 256) {
        int row = i >> 4, seg = (i & 15) * 8;
        int n = n0 + row;
        uint4 w = make_uint4(0u, 0u, 0u, 0u);
        if (n < N_NODES) w = *(const uint4*)(h + (long)n * DIM + seg);
        *(uint4*)&a_lds[row][seg] = w;
    }
    __syncthreads();
    int wv = tx >> 6, lane = tx & 63;
    int m16 = lane & 15, quad = lane >> 4;
    f32x4 acc[8];
#pragma unroll
    for (int c = 0; c < 8; c++) acc[c] = (f32x4){0.f, 0.f, 0.f, 0.f};
    for (int ks = 0; ks < 4; ks++) {
        int koff = ks * 32 + quad * 8;
        bf16x8 af = *(const bf16x8*)(const void*)&a_lds[wv * 16 + m16][koff];
#pragma unroll
        for (int c = 0; c < 8; c++) {
            bf16x8 bfr = *(const bf16x8*)(const void*)&b_lds[c * 16 + m16][koff];
            acc[c] = __builtin_amdgcn_mfma_f32_16x16x32_bf16(af, bfr, acc[c], 0, 0, 0);
        }
    }
#pragma unroll
    for (int c = 0; c < 8; c++) {
#pragma unroll
        for (int i = 0; i < 4; i++) {
            int row = wv * 16 + quad * 4 + i;
            int col = c * 16 + m16;
            int n = n0 + row;
            if (n < N_NODES)
                P[(long)n * (RR * DIM) + r * DIM + col] = f_to_bf16(acc[c][i]);
        }
    }
}

// ---------- gather: 4 edges in flight per wave ----------
__global__ void cg_gather4(const unsigned short* __restrict__ P, const int* __restrict__ rowptr,
                           const int* __restrict__ eidx, const float* __restrict__ cv,
                           unsigned short* __restrict__ hout) {
    int wid  = (blockIdx.x * 256 + threadIdx.x) >> 6;
    int lane = threadIdx.x & 63;
    if (wid >= N_NODES) return;
    int eg = lane >> 4;
    int ol = lane & 15;
    int start = rowptr[wid];
    int end   = rowptr[wid + 1];
    float a[8] = {0.f, 0.f, 0.f, 0.f, 0.f, 0.f, 0.f, 0.f};
    for (int j = start + eg; j < end; j += 4) {
        int v = eidx[j];
        const uint4 w = *(const uint4*)(P + (long)(v >> 2) * (RR * DIM) + (v & 3) * DIM + ol * 8);
        a[0] += bf16_to_f((unsigned short)(w.x & 0xFFFFu));
        a[1] += bf16_to_f((unsigned short)(w.x >> 16));
        a[2] += bf16_to_f((unsigned short)(w.y & 0xFFFFu));
        a[3] += bf16_to_f((unsigned short)(w.y >> 16));
        a[4] += bf16_to_f((unsigned short)(w.z & 0xFFFFu));
        a[5] += bf16_to_f((unsigned short)(w.z >> 16));
        a[6] += bf16_to_f((unsigned short)(w.w & 0xFFFFu));
        a[7] += bf16_to_f((unsigned short)(w.w >> 16));
    }
#pragma unroll
    for (int i = 0; i < 8; i++) {
        a[i] += __shfl_xor(a[i], 16);
        a[i] += __shfl_xor(a[i], 32);
    }
    if (eg == 0) {
        int o0 = ol * 8;
        float v[8];
#pragma unroll
        for (int i = 0; i < 8; i++) {
            float s = a[i] + cv[o0 + i];
            v[i] = s > 0.0f ? s : 0.0f;
        }
        uint4 o4;
        o4.x = (unsigned int)f_to_bf16(v[0]) | ((unsigned int)f_to_bf16(v[1]) << 16);
        o4.y = (unsigned int)f_to_bf16(v[2]) | ((unsigned int)f_to_bf16(v[3]) << 16);
        o4.z = (unsigned int)f_to_bf16(v[4]) | ((unsigned int)f_to_bf16(v[5]) << 16);
        o4.w = (unsigned int)f_to_bf16(v[6]) | ((unsigned int)f_to_bf16(v[7]) << 16);
        *(uint4*)(hout + (long)wid * DIM + o0) = o4;
    }
}

// ---------- pooling via sorted-batch binary search ----------
__global__ void cg_pool2(const unsigned short* __restrict__ h, const int* __restrict__ batch,
                         float* __restrict__ embacc, const int* __restrict__ flagp,
                         void* __restrict__ out) {
    int g = blockIdx.x;
    int o = threadIdx.x;
    int lo = 0, hi = N_NODES;
    while (lo < hi) { int mid = (lo + hi) >> 1; if (batch[mid] < g) lo = mid + 1; else hi = mid; }
    int start = lo;
    hi = N_NODES;
    while (lo < hi) { int mid = (lo + hi) >> 1; if (batch[mid] < g + 1) lo = mid + 1; else hi = mid; }
    int end = lo;
    float acc = 0.0f;
    for (int n = start; n < end; n++) acc += bf16_to_f(h[(long)n * DIM + o]);
    int cnt = end - start;
    float e = acc / (float)(cnt > 1 ? cnt : 1);
    embacc[(long)g * DIM + o] = e;
    storef(out, (long)g * DIM + o, e, *flagp);
}

// ---------- logits ----------
__global__ void cg_logits(const float* __restrict__ emb, const void* __restrict__ cls_W,
                          const void* __restrict__ cls_b, const int* __restrict__ flagp,
                          void* __restrict__ out) {
    int t = blockIdx.x * 256 + threadIdx.x;
    if (t >= GG * CC) return;
    int g  = t >> 3;
    int cc = t & 7;
    int isbf = *flagp;
    float acc = loadf(cls_b, cc, isbf);
    for (int k = 0; k < DIM; k++) {
        acc += emb[(long)g * DIM + k] * loadf(cls_W, (long)k * CC + cc, isbf);
    }
    storef(out, (long)GG * DIM + t, acc, isbf);
}

extern "C" void kernel_launch(void* const* d_in, const int* in_sizes, int n_in,
                              void* d_out, int out_size, void* d_ws, size_t ws_size,
                              hipStream_t stream) {
    const void* x      = d_in[0];
    const void* W_het  = d_in[1];
    const void* b_het  = d_in[2];
    const void* conv_W = d_in[3];
    const void* conv_b = d_in[4];
    const void* fuse_W = d_in[5];
    const void* fuse_b = d_in[6];
    const void* cls_W  = d_in[7];
    const void* cls_b  = d_in[8];
    const int* node_type  = (const int*)d_in[9];
    const int* edge_index = (const int*)d_in[10];
    const int* edge_type  = (const int*)d_in[11];
    const int* batch      = (const int*)d_in[12];

    // workspace layout (bytes, 16B aligned); deg and tb adjacent for one zero pass
    char* base = (char*)d_ws;
    unsigned short* hbf      = (unsigned short*)(base + 0);          // 12,800,000
    unsigned short* P        = (unsigned short*)(base + 12800000);   // 51,200,000
    unsigned short* xb       = (unsigned short*)(base + 64000000);   // 12,800,000
    unsigned short* Wt       = (unsigned short*)(base + 76800000);   //    131,072
    float*          bhf      = (float*)(base + 76931072);            //      2,048
    unsigned short* M2t      = (unsigned short*)(base + 76933120);   //    262,144
    float*          cvec     = (float*)(base + 77195264);            //      1,024
    float*          embacc   = (float*)(base + 77196288);            //    262,144
    int*            rowptr   = (int*)(base + 77458432);              //    200,032
    int*            cursor   = (int*)(base + 77658464);              //    200,032
    int*            deg      = (int*)(base + 77858496);              //    200,000
    int*            tb       = (int*)(base + 78058496);              //         64
    int*            blocksum = (int*)(base + 78058560);              //      1,024
    int*            blockoff = (int*)(base + 78059584);              //      1,024
    int*            eidx     = (int*)(base + 78060608);              //  2,400,000
    int*            tlist    = (int*)(base + 80460608);              //    200,000
    int*            flag     = (int*)(base + 80660608);              //          4

    cg_detect<<<1, 256, 0, stream>>>((const unsigned int*)x, flag);

    // graph structure
    cg_zero_i<<<(N_NODES + 16 + 255) / 256, 256, 0, stream>>>(deg, N_NODES + 16);
    cg_hist2<<<(N_EDGES + 255) / 256, 256, 0, stream>>>(edge_index, node_type, deg, tb);
    cg_scan_a<<<NB_SCAN, 256, 0, stream>>>(deg, blocksum);
    cg_scan_b<<<1, 256, 0, stream>>>(blocksum, blockoff, rowptr, tb);
    cg_scan_c<<<NB_SCAN, 256, 0, stream>>>(deg, blockoff, rowptr, cursor);
    cg_fill<<<(N_EDGES + 255) / 256, 256, 0, stream>>>(edge_index, edge_type, cursor, eidx);
    cg_tfill<<<(N_NODES + 255) / 256, 256, 0, stream>>>(node_type, tb, tlist);

    // canonicalization
    cg_canon_x<<<(int)(((long)N_NODES * DIM + 255) / 256), 256, 0, stream>>>(x, flag, xb);
    cg_canon_W<<<4 * DIM, DIM, 0, stream>>>(W_het, flag, Wt);
    cg_canon_bh<<<4, DIM, 0, stream>>>(b_het, flag, bhf);
    cg_make_M2t<<<LL * RR * DIM, DIM, 0, stream>>>(conv_W, fuse_W, flag, M2t);
    cg_make_c<<<LL * DIM, 256, 0, stream>>>(conv_b, fuse_W, fuse_b, flag, cvec);

    // pipeline
    cg_hetero_mfma<<<dim3((N_NODES + 63) / 64, 4), 256, 0, stream>>>(
        xb, Wt, bhf, tlist, tb, hbf);
    for (int l = 0; l < LL; l++) {
        cg_pgemm_mfma<<<dim3((N_NODES + 63) / 64, RR), 256, 0, stream>>>(hbf, M2t, l, P);
        cg_gather4<<<(N_NODES * 64 + 255) / 256, 256, 0, stream>>>(
            P, rowptr, eidx, cvec + l * DIM, hbf);
    }

    cg_pool2<<<GG, DIM, 0, stream>>>(hbf, batch, embacc, flag, d_out);
    cg_logits<<<(GG * CC + 255) / 256, 256, 0, stream>>>(embacc, cls_W, cls_b, flag, d_out);
}

// Round 10
// 354.943 us; speedup vs baseline: 3.1013x; 1.1488x over previous
//
#include <hip/hip_runtime.h>

#define N_NODES 50000
#define N_EDGES 600000
#define DIM     128
#define RR      4
#define LL      2
#define GG      512
#define CC      8
#define NB_SCAN ((N_NODES + 255) / 256)   // 196

typedef short bf16x8 __attribute__((ext_vector_type(8)));
typedef float f32x4  __attribute__((ext_vector_type(4)));

// ---------- bf16 <-> f32 helpers ----------
__device__ __forceinline__ float bf16_to_f(unsigned short u) {
    return __uint_as_float(((unsigned int)u) << 16);
}
__device__ __forceinline__ unsigned short f_to_bf16(float f) {
    unsigned int u = __float_as_uint(f);
    u += 0x7FFFu + ((u >> 16) & 1u);   // RNE
    return (unsigned short)(u >> 16);
}
__device__ __forceinline__ float loadf(const void* p, long i, int isbf) {
    if (isbf) return bf16_to_f(((const unsigned short*)p)[i]);
    return ((const float*)p)[i];
}
__device__ __forceinline__ void storef(void* p, long i, float v, int isbf) {
    if (isbf) ((unsigned short*)p)[i] = f_to_bf16(v);
    else      ((float*)p)[i] = v;
}

// ---------- init: zero deg+tb, and (block 0) dtype-detect ----------
__global__ void cg_init(const unsigned int* __restrict__ xw, int* __restrict__ flag,
                        int* __restrict__ deg_tb) {
    __shared__ int cnt;
    int tid = threadIdx.x;
    int t = blockIdx.x * 256 + tid;
    if (t < N_NODES + 16) deg_tb[t] = 0;
    if (blockIdx.x == 0) {
        if (tid == 0) cnt = 0;
        __syncthreads();
        unsigned int w = xw[tid];
        unsigned int e = (w >> 7) & 0xFFu;
        atomicAdd(&cnt, (e >= 110u && e <= 133u) ? 1 : 0);
        __syncthreads();
        if (tid == 0) *flag = (cnt >= 128) ? 1 : 0;
    }
}

// ---------- histograms: edge-dst degree + node-type (block-aggregated) ----------
__global__ void cg_hist2(const int* __restrict__ edge_index, const int* __restrict__ node_type,
                         int* __restrict__ deg, int* __restrict__ tb) {
    __shared__ int loc[4];
    int tid = threadIdx.x;
    if (tid < 4) loc[tid] = 0;
    __syncthreads();
    int e = blockIdx.x * 256 + tid;
    if (e < N_EDGES) atomicAdd(&deg[edge_index[N_EDGES + e]], 1);
    if (e < N_NODES) atomicAdd(&loc[node_type[e]], 1);
    __syncthreads();
    if (tid < 4 && loc[tid]) atomicAdd(&tb[tid], loc[tid]);
}

// ---------- device-wide exclusive scan, 3 phases ----------
__global__ void cg_scan_a(const int* __restrict__ deg, int* __restrict__ blocksum) {
    __shared__ int s[256];
    int tid = threadIdx.x;
    int i = blockIdx.x * 256 + tid;
    s[tid] = (i < N_NODES) ? deg[i] : 0;
    __syncthreads();
    for (int off = 128; off > 0; off >>= 1) {
        if (tid < off) s[tid] += s[tid + off];
        __syncthreads();
    }
    if (tid == 0) blocksum[blockIdx.x] = s[0];
}

__global__ void cg_scan_b(const int* __restrict__ blocksum, int* __restrict__ blockoff,
                          int* __restrict__ rowptr, int* __restrict__ tb) {
    __shared__ int s[256];
    int tid = threadIdx.x;
    int v = (tid < NB_SCAN) ? blocksum[tid] : 0;
    s[tid] = v;
    __syncthreads();
    for (int off = 1; off < 256; off <<= 1) {
        int a = (tid >= off) ? s[tid - off] : 0;
        __syncthreads();
        s[tid] += a;
        __syncthreads();
    }
    if (tid < NB_SCAN) blockoff[tid] = s[tid] - v;   // exclusive
    if (tid == 255) rowptr[N_NODES] = s[255];        // total = E
    if (tid == 0) {                                   // fold the tiny type-bucket scan
        int run = 0;
        for (int t = 0; t < 4; t++) {
            tb[8 + t] = run;
            tb[4 + t] = run;
            run += tb[t];
        }
        tb[12] = run;
    }
}

__global__ void cg_scan_c(const int* __restrict__ deg, const int* __restrict__ blockoff,
                          int* __restrict__ rowptr, int* __restrict__ cursor) {
    __shared__ int s[256];
    int tid = threadIdx.x;
    int i = blockIdx.x * 256 + tid;
    int v = (i < N_NODES) ? deg[i] : 0;
    s[tid] = v;
    __syncthreads();
    for (int off = 1; off < 256; off <<= 1) {
        int a = (tid >= off) ? s[tid - off] : 0;
        __syncthreads();
        s[tid] += a;
        __syncthreads();
    }
    if (i < N_NODES) {
        int val = blockoff[blockIdx.x] + s[tid] - v;  // exclusive
        rowptr[i] = val;
        cursor[i] = val;
    }
}

__global__ void cg_fill(const int* __restrict__ edge_index, const int* __restrict__ edge_type,
                        int* __restrict__ cursor, int* __restrict__ eidx) {
    int e = blockIdx.x * 256 + threadIdx.x;
    if (e >= N_EDGES) return;
    int d = edge_index[N_EDGES + e];
    int pos = atomicAdd(&cursor[d], 1);
    eidx[pos] = (edge_index[e] << 2) | edge_type[e];
}

// ---------- node-type list fill (block-aggregated) ----------
__global__ void cg_tfill(const int* __restrict__ node_type, int* __restrict__ tb,
                         int* __restrict__ tlist) {
    __shared__ int lcur[4];
    __shared__ int lbase[4];
    int tid = threadIdx.x;
    if (tid < 4) lcur[tid] = 0;
    __syncthreads();
    int n = blockIdx.x * 256 + tid;
    int slot = -1, t = 0;
    if (n < N_NODES) {
        t = node_type[n];
        slot = atomicAdd(&lcur[t], 1);
    }
    __syncthreads();
    if (tid < 4) lbase[tid] = atomicAdd(&tb[4 + tid], lcur[tid]);
    __syncthreads();
    if (n < N_NODES) tlist[lbase[t] + slot] = n;
}

// ---------- canonicalize x -> packed bf16 ----------
__global__ void cg_canon_x(const void* __restrict__ x, const int* __restrict__ flagp,
                           unsigned short* __restrict__ xb) {
    long t = (long)blockIdx.x * 256 + threadIdx.x;
    if (t >= (long)N_NODES * DIM) return;
    int isbf = *flagp;
    if (isbf) xb[t] = ((const unsigned short*)x)[t];
    else      xb[t] = f_to_bf16(((const float*)x)[t]);
}

// ---------- canon W_het (transposed, bf16) + b_het (fp32) in one kernel ----------
__global__ void cg_canon_Wb(const void* __restrict__ W_het, const void* __restrict__ b_het,
                            const int* __restrict__ flagp,
                            unsigned short* __restrict__ Wt, float* __restrict__ bhf) {
    int b = blockIdx.x;
    int isbf = *flagp;
    if (b < 4 * DIM) {           // Wt[t][o][d] = bf16(W_het[t][d][o])
        int o = b & 127;
        int t = b >> 7;
        int d = threadIdx.x;
        float v = loadf(W_het, ((long)t * DIM + d) * DIM + o, isbf);
        Wt[((long)t * DIM + o) * DIM + d] = f_to_bf16(v);
    } else {                      // bhf[t][o]
        int t = b - 4 * DIM;
        int o = threadIdx.x;
        bhf[t * DIM + o] = loadf(b_het, t * DIM + o, isbf);
    }
}

// ---------- M2t + cvec in one kernel (256 threads both paths) ----------
// blocks 0..511:   M2t[lr][o][d] = bf16( sum_k conv_W[l,r,d,k] * fuse_W[r*128+k,o] )
//                  (two d-rows per block)
// blocks 512..767: cvec[l*128+o] = sum_rk conv_b[l,rk]*fuse_W[rk,o] + fuse_b[o]
__global__ void cg_make_M2tc(const void* __restrict__ conv_W, const void* __restrict__ fuse_W,
                             const void* __restrict__ conv_b, const void* __restrict__ fuse_b,
                             const int* __restrict__ flagp,
                             unsigned short* __restrict__ M2t, float* __restrict__ cvec) {
    __shared__ float s[256];
    int b = blockIdx.x;
    int tid = threadIdx.x;
    int isbf = *flagp;
    if (b < 512) {
        int lr = b >> 6;                       // 8 lr values, 64 blocks each
        int d  = (b & 63) * 2 + (tid >> 7);    // two d per block
        int r  = lr & 3;
        int o  = tid & 127;
        float acc = 0.0f;
        for (int k = 0; k < DIM; k++) {
            acc += loadf(conv_W, (long)(lr * DIM + d) * DIM + k, isbf)
                 * loadf(fuse_W, (long)(r * DIM + k) * DIM + o, isbf);
        }
        M2t[((long)lr * DIM + o) * DIM + d] = f_to_bf16(acc);
    } else {
        int bc = b - 512;                      // l*DIM + o
        int l  = bc >> 7;
        int o  = bc & 127;
        float part = 0.0f;
        for (int rk = tid; rk < RR * DIM; rk += 256) {
            part += loadf(conv_b, (long)l * RR * DIM + rk, isbf)
                  * loadf(fuse_W, (long)rk * DIM + o, isbf);
        }
        s[tid] = part;
        __syncthreads();
        for (int off = 128; off > 0; off >>= 1) {
            if (tid < off) s[tid] += s[tid + off];
            __syncthreads();
        }
        if (tid == 0) cvec[bc] = s[0] + loadf(fuse_b, o, isbf);
    }
}

// ================= MFMA GEMM kernels =================
#define APAD 136

__global__ void cg_hetero_mfma(const unsigned short* __restrict__ xb,
                               const unsigned short* __restrict__ Wt,
                               const float* __restrict__ bhf,
                               const int* __restrict__ tlist, const int* __restrict__ tb,
                               unsigned short* __restrict__ h) {
    int t = blockIdx.y;
    int rows_base = tb[8 + t] + blockIdx.x * 64;
    int rend = tb[8 + t + 1];
    if (rows_base >= rend) return;
    __shared__ unsigned short a_lds[64][APAD];
    __shared__ unsigned short b_lds[DIM][APAD];
    int tx = threadIdx.x;
    const unsigned short* Wsrc = Wt + (long)t * DIM * DIM;
    for (int i = tx; i < 2048; i += 256) {
        uint4 w = *(const uint4*)(Wsrc + i * 8);
        int o = i >> 4, d = (i & 15) * 8;
        *(uint4*)&b_lds[o][d] = w;
    }
    for (int i = tx; i < 1024; i += 256) {
        int row = i >> 4, seg = (i & 15) * 8;
        int gr = rows_base + row;
        uint4 w = make_uint4(0u, 0u, 0u, 0u);
        if (gr < rend) {
            int n = tlist[gr];
            w = *(const uint4*)(xb + (long)n * DIM + seg);
        }
        *(uint4*)&a_lds[row][seg] = w;
    }
    __syncthreads();
    int wv = tx >> 6, lane = tx & 63;
    int m16 = lane & 15, quad = lane >> 4;
    f32x4 acc[8];
#pragma unroll
    for (int c = 0; c < 8; c++) acc[c] = (f32x4){0.f, 0.f, 0.f, 0.f};
    for (int ks = 0; ks < 4; ks++) {
        int koff = ks * 32 + quad * 8;
        bf16x8 af = *(const bf16x8*)(const void*)&a_lds[wv * 16 + m16][koff];
#pragma unroll
        for (int c = 0; c < 8; c++) {
            bf16x8 bfr = *(const bf16x8*)(const void*)&b_lds[c * 16 + m16][koff];
            acc[c] = __builtin_amdgcn_mfma_f32_16x16x32_bf16(af, bfr, acc[c], 0, 0, 0);
        }
    }
#pragma unroll
    for (int c = 0; c < 8; c++) {
#pragma unroll
        for (int i = 0; i < 4; i++) {
            int row = wv * 16 + quad * 4 + i;
            int col = c * 16 + m16;
            int gr = rows_base + row;
            if (gr < rend) {
                int n = tlist[gr];
                h[(long)n * DIM + col] = f_to_bf16(acc[c][i] + bhf[t * DIM + col]);
            }
        }
    }
}

__global__ void cg_pgemm_mfma(const unsigned short* __restrict__ h,
                              const unsigned short* __restrict__ M2t, int l,
                              unsigned short* __restrict__ P) {
    int r  = blockIdx.y;
    int n0 = blockIdx.x * 64;
    __shared__ unsigned short a_lds[64][APAD];
    __shared__ unsigned short b_lds[DIM][APAD];
    int tx = threadIdx.x;
    const unsigned short* Bsrc = M2t + (long)(l * RR + r) * DIM * DIM;
    for (int i = tx; i < 2048; i += 256) {
        uint4 w = *(const uint4*)(Bsrc + i * 8);
        int o = i >> 4, d = (i & 15) * 8;
        *(uint4*)&b_lds[o][d] = w;
    }
    for (int i = tx; i < 1024; i += 256) {
        int row = i >> 4, seg = (i & 15) * 8;
        int n = n0 + row;
        uint4 w = make_uint4(0u, 0u, 0u, 0u);
        if (n < N_NODES) w = *(const uint4*)(h + (long)n * DIM + seg);
        *(uint4*)&a_lds[row][seg] = w;
    }
    __syncthreads();
    int wv = tx >> 6, lane = tx & 63;
    int m16 = lane & 15, quad = lane >> 4;
    f32x4 acc[8];
#pragma unroll
    for (int c = 0; c < 8; c++) acc[c] = (f32x4){0.f, 0.f, 0.f, 0.f};
    for (int ks = 0; ks < 4; ks++) {
        int koff = ks * 32 + quad * 8;
        bf16x8 af = *(const bf16x8*)(const void*)&a_lds[wv * 16 + m16][koff];
#pragma unroll
        for (int c = 0; c < 8; c++) {
            bf16x8 bfr = *(const bf16x8*)(const void*)&b_lds[c * 16 + m16][koff];
            acc[c] = __builtin_amdgcn_mfma_f32_16x16x32_bf16(af, bfr, acc[c], 0, 0, 0);
        }
    }
#pragma unroll
    for (int c = 0; c < 8; c++) {
#pragma unroll
        for (int i = 0; i < 4; i++) {
            int row = wv * 16 + quad * 4 + i;
            int col = c * 16 + m16;
            int n = n0 + row;
            if (n < N_NODES)
                P[(long)n * (RR * DIM) + r * DIM + col] = f_to_bf16(acc[c][i]);
        }
    }
}

// ---------- gather: 4 edges in flight per wave ----------
__global__ void cg_gather4(const unsigned short* __restrict__ P, const int* __restrict__ rowptr,
                           const int* __restrict__ eidx, const float* __restrict__ cv,
                           unsigned short* __restrict__ hout) {
    int wid  = (blockIdx.x * 256 + threadIdx.x) >> 6;
    int lane = threadIdx.x & 63;
    if (wid >= N_NODES) return;
    int eg = lane >> 4;
    int ol = lane & 15;
    int start = rowptr[wid];
    int end   = rowptr[wid + 1];
    float a[8] = {0.f, 0.f, 0.f, 0.f, 0.f, 0.f, 0.f, 0.f};
    for (int j = start + eg; j < end; j += 4) {
        int v = eidx[j];
        const uint4 w = *(const uint4*)(P + (long)(v >> 2) * (RR * DIM) + (v & 3) * DIM + ol * 8);
        a[0] += bf16_to_f((unsigned short)(w.x & 0xFFFFu));
        a[1] += bf16_to_f((unsigned short)(w.x >> 16));
        a[2] += bf16_to_f((unsigned short)(w.y & 0xFFFFu));
        a[3] += bf16_to_f((unsigned short)(w.y >> 16));
        a[4] += bf16_to_f((unsigned short)(w.z & 0xFFFFu));
        a[5] += bf16_to_f((unsigned short)(w.z >> 16));
        a[6] += bf16_to_f((unsigned short)(w.w & 0xFFFFu));
        a[7] += bf16_to_f((unsigned short)(w.w >> 16));
    }
#pragma unroll
    for (int i = 0; i < 8; i++) {
        a[i] += __shfl_xor(a[i], 16);
        a[i] += __shfl_xor(a[i], 32);
    }
    if (eg == 0) {
        int o0 = ol * 8;
        float v[8];
#pragma unroll
        for (int i = 0; i < 8; i++) {
            float s = a[i] + cv[o0 + i];
            v[i] = s > 0.0f ? s : 0.0f;
        }
        uint4 o4;
        o4.x = (unsigned int)f_to_bf16(v[0]) | ((unsigned int)f_to_bf16(v[1]) << 16);
        o4.y = (unsigned int)f_to_bf16(v[2]) | ((unsigned int)f_to_bf16(v[3]) << 16);
        o4.z = (unsigned int)f_to_bf16(v[4]) | ((unsigned int)f_to_bf16(v[5]) << 16);
        o4.w = (unsigned int)f_to_bf16(v[6]) | ((unsigned int)f_to_bf16(v[7]) << 16);
        *(uint4*)(hout + (long)wid * DIM + o0) = o4;
    }
}

// ---------- fused mean-pool + logits: one block per graph ----------
__global__ void cg_pool_logits(const unsigned short* __restrict__ h, const int* __restrict__ batch,
                               const void* __restrict__ cls_W, const void* __restrict__ cls_b,
                               const int* __restrict__ flagp, void* __restrict__ out) {
    __shared__ float acc_s[4][DIM];
    __shared__ float emb_s[DIM];
    int g   = blockIdx.x;
    int tid = threadIdx.x;
    int wv  = tid >> 6;       // 0..3
    int lane = tid & 63;
    int sub = lane >> 4;      // node offset within wave iteration
    int ol  = lane & 15;      // cols ol*8 .. ol*8+7
    int isbf = *flagp;
    // [start,end) of graph g in sorted batch
    int lo = 0, hi = N_NODES;
    while (lo < hi) { int mid = (lo + hi) >> 1; if (batch[mid] < g) lo = mid + 1; else hi = mid; }
    int start = lo;
    hi = N_NODES;
    while (lo < hi) { int mid = (lo + hi) >> 1; if (batch[mid] < g + 1) lo = mid + 1; else hi = mid; }
    int end = lo;
    float a[8] = {0.f, 0.f, 0.f, 0.f, 0.f, 0.f, 0.f, 0.f};
    for (int n = start + wv * 4 + sub; n < end; n += 16) {
        uint4 w = *(const uint4*)(h + (long)n * DIM + ol * 8);
        a[0] += bf16_to_f((unsigned short)(w.x & 0xFFFFu));
        a[1] += bf16_to_f((unsigned short)(w.x >> 16));
        a[2] += bf16_to_f((unsigned short)(w.y & 0xFFFFu));
        a[3] += bf16_to_f((unsigned short)(w.y >> 16));
        a[4] += bf16_to_f((unsigned short)(w.z & 0xFFFFu));
        a[5] += bf16_to_f((unsigned short)(w.z >> 16));
        a[6] += bf16_to_f((unsigned short)(w.w & 0xFFFFu));
        a[7] += bf16_to_f((unsigned short)(w.w >> 16));
    }
#pragma unroll
    for (int i = 0; i < 8; i++) {
        a[i] += __shfl_xor(a[i], 16);
        a[i] += __shfl_xor(a[i], 32);
    }
    if (sub == 0) {
#pragma unroll
        for (int i = 0; i < 8; i++) acc_s[wv][ol * 8 + i] = a[i];
    }
    __syncthreads();
    int cnt = end - start;
    float inv = 1.0f / (float)(cnt > 1 ? cnt : 1);
    if (tid < DIM) {
        float e = (acc_s[0][tid] + acc_s[1][tid] + acc_s[2][tid] + acc_s[3][tid]) * inv;
        emb_s[tid] = e;
        storef(out, (long)g * DIM + tid, e, isbf);
    }
    __syncthreads();
    if (tid < 128) {
        int c  = tid >> 4;   // 0..7
        int kk = tid & 15;
        float p = 0.0f;
#pragma unroll
        for (int k = kk * 8; k < kk * 8 + 8; k++)
            p += emb_s[k] * loadf(cls_W, (long)k * CC + c, isbf);
        p += __shfl_xor(p, 1);
        p += __shfl_xor(p, 2);
        p += __shfl_xor(p, 4);
        p += __shfl_xor(p, 8);
        if (kk == 0)
            storef(out, (long)GG * DIM + g * CC + c, p + loadf(cls_b, c, isbf), isbf);
    }
}

extern "C" void kernel_launch(void* const* d_in, const int* in_sizes, int n_in,
                              void* d_out, int out_size, void* d_ws, size_t ws_size,
                              hipStream_t stream) {
    const void* x      = d_in[0];
    const void* W_het  = d_in[1];
    const void* b_het  = d_in[2];
    const void* conv_W = d_in[3];
    const void* conv_b = d_in[4];
    const void* fuse_W = d_in[5];
    const void* fuse_b = d_in[6];
    const void* cls_W  = d_in[7];
    const void* cls_b  = d_in[8];
    const int* node_type  = (const int*)d_in[9];
    const int* edge_index = (const int*)d_in[10];
    const int* edge_type  = (const int*)d_in[11];
    const int* batch      = (const int*)d_in[12];

    // workspace layout (bytes, 16B aligned); deg and tb adjacent for one zero pass
    char* base = (char*)d_ws;
    unsigned short* hbf      = (unsigned short*)(base + 0);          // 12,800,000
    unsigned short* P        = (unsigned short*)(base + 12800000);   // 51,200,000
    unsigned short* xb       = (unsigned short*)(base + 64000000);   // 12,800,000
    unsigned short* Wt       = (unsigned short*)(base + 76800000);   //    131,072
    float*          bhf      = (float*)(base + 76931072);            //      2,048
    unsigned short* M2t      = (unsigned short*)(base + 76933120);   //    262,144
    float*          cvec     = (float*)(base + 77195264);            //      1,024
    int*            rowptr   = (int*)(base + 77196288);              //    200,032
    int*            cursor   = (int*)(base + 77396320);              //    200,032
    int*            deg      = (int*)(base + 77596352);              //    200,000
    int*            tb       = (int*)(base + 77796352);              //         64
    int*            blocksum = (int*)(base + 77796416);              //      1,024
    int*            blockoff = (int*)(base + 77797440);              //      1,024
    int*            eidx     = (int*)(base + 77798464);              //  2,400,000
    int*            tlist    = (int*)(base + 80198464);              //    200,000
    int*            flag     = (int*)(base + 80398464);              //          4

    // graph structure + dtype detect
    cg_init<<<(N_NODES + 16 + 255) / 256, 256, 0, stream>>>((const unsigned int*)x, flag, deg);
    cg_hist2<<<(N_EDGES + 255) / 256, 256, 0, stream>>>(edge_index, node_type, deg, tb);
    cg_scan_a<<<NB_SCAN, 256, 0, stream>>>(deg, blocksum);
    cg_scan_b<<<1, 256, 0, stream>>>(blocksum, blockoff, rowptr, tb);
    cg_scan_c<<<NB_SCAN, 256, 0, stream>>>(deg, blockoff, rowptr, cursor);
    cg_fill<<<(N_EDGES + 255) / 256, 256, 0, stream>>>(edge_index, edge_type, cursor, eidx);
    cg_tfill<<<(N_NODES + 255) / 256, 256, 0, stream>>>(node_type, tb, tlist);

    // canonicalization
    cg_canon_x<<<(int)(((long)N_NODES * DIM + 255) / 256), 256, 0, stream>>>(x, flag, xb);
    cg_canon_Wb<<<4 * DIM + 4, DIM, 0, stream>>>(W_het, b_het, flag, Wt, bhf);
    cg_make_M2tc<<<768, 256, 0, stream>>>(conv_W, fuse_W, conv_b, fuse_b, flag, M2t, cvec);

    // pipeline
    cg_hetero_mfma<<<dim3((N_NODES + 63) / 64, 4), 256, 0, stream>>>(
        xb, Wt, bhf, tlist, tb, hbf);
    for (int l = 0; l < LL; l++) {
        cg_pgemm_mfma<<<dim3((N_NODES + 63) / 64, RR), 256, 0, stream>>>(hbf, M2t, l, P);
        cg_gather4<<<(N_NODES * 64 + 255) / 256, 256, 0, stream>>>(
            P, rowptr, eidx, cvec + l * DIM, hbf);
    }

    cg_pool_logits<<<GG, 256, 0, stream>>>(hbf, batch, cls_W, cls_b, flag, d_out);
}